// Round 2
// baseline (3833.519 us; speedup 1.0000x reference)
//
#include <hip/hip_runtime.h>
#include <cstdint>
#include <cstddef>

typedef unsigned short u16;
typedef unsigned int u32;

typedef __bf16 bf8_t __attribute__((ext_vector_type(8)));
typedef float f4_t __attribute__((ext_vector_type(4)));

__device__ __forceinline__ u16 f2bf(float x) {
  u32 u = __float_as_uint(x);
  u = (u + 0x7fffu + ((u >> 16) & 1u)) >> 16;
  return (u16)u;
}
__device__ __forceinline__ float bf2f(u16 x) {
  u32 u = ((u32)x) << 16;
  return __uint_as_float(u);
}
__device__ __forceinline__ float sigf(float x) { return 1.f / (1.f + __expf(-x)); }

#define MFMA16(a, b, c) __builtin_amdgcn_mfma_f32_16x16x32_bf16(a, b, c, 0, 0, 0)

// ---------------- fill (sentinel) ----------------
__global__ void fill_kernel(float* p, float v, long n) {
  long i = (long)blockIdx.x * blockDim.x + threadIdx.x;
  if (i < n) p[i] = v;
}

// ---------------- fp32 -> bf16 weight convert with zero padding ----------------
__global__ void padcvt_kernel(const float* __restrict__ src, u16* __restrict__ dst,
                              int rows, int cols, int pc, long total) {
  long i = (long)blockIdx.x * blockDim.x + threadIdx.x;
  if (i >= total) return;
  int r = (int)(i / pc), c = (int)(i % pc);
  float v = (r < rows && c < cols) ? src[(long)r * cols + c] : 0.f;
  dst[i] = f2bf(v);
}

// ---------------- token-shift mix ----------------
__global__ void mix1_kernel(const float* __restrict__ h_b, const float* __restrict__ coef,
                            u16* __restrict__ out_seg, int t0, int Tc, long total4) {
  long i = (long)blockIdx.x * blockDim.x + threadIdx.x;
  if (i >= total4) return;
  long e = i * 4;
  const int H = 2048;
  int col = (int)(e % H);
  int tl = (int)(e / H);
  int tg = t0 + tl;
  const float* hp = h_b + (long)tg * H + col;
  float4 hv = *(const float4*)hp;
  float4 pv = make_float4(0.f, 0.f, 0.f, 0.f);
  if (tg > 0) pv = *(const float4*)(hp - H);
  float4 cc = *(const float4*)(coef + col);
  uint2 pk;
  pk.x = (u32)f2bf(hv.x + (pv.x - hv.x) * cc.x) | ((u32)f2bf(hv.y + (pv.y - hv.y) * cc.y) << 16);
  pk.y = (u32)f2bf(hv.z + (pv.z - hv.z) * cc.z) | ((u32)f2bf(hv.w + (pv.w - hv.w) * cc.w) << 16);
  *(uint2*)(out_seg + e) = pk;
}

// ---------------- bf16 MFMA GEMM (128x128, small-N / special epilogues) ----------------
// MODE 0: fp32. 1: bf16. 2: tanh->bf16. 3: sigmoid->bf16. 4: fp32 lerp epilogue.
#define LDSW 40
template <int MODE>
__global__ __launch_bounds__(256) void gemm_bt(
    const u16* __restrict__ A, const u16* __restrict__ B, void* __restrict__ Cv,
    int M, int N, int K, const float* __restrict__ aux0, const float* __restrict__ aux1) {
  __shared__ u16 sA[128 * LDSW];
  __shared__ u16 sB[128 * LDSW];
  const int tid = threadIdx.x;
  const long bm = (long)blockIdx.y * 128;
  const long bn = (long)blockIdx.x * 128;
  const int wave = tid >> 6, lane = tid & 63;
  const int wm = (wave >> 1) * 64, wn = (wave & 1) * 64;
  const int quad = lane >> 4, rr = lane & 15;

  f4_t acc[4][4];
  const f4_t zero = {0.f, 0.f, 0.f, 0.f};
#pragma unroll
  for (int i = 0; i < 4; i++)
#pragma unroll
    for (int j = 0; j < 4; j++) acc[i][j] = zero;

  const int c0 = tid, c1 = tid + 256;
  for (int k0 = 0; k0 < K; k0 += 32) {
    __syncthreads();
    {
      const uint4 a0 = *(const uint4*)(A + (bm + (c0 >> 2)) * (long)K + k0 + (c0 & 3) * 8);
      const uint4 a1 = *(const uint4*)(A + (bm + (c1 >> 2)) * (long)K + k0 + (c1 & 3) * 8);
      const uint4 b0 = *(const uint4*)(B + (bn + (c0 >> 2)) * (long)K + k0 + (c0 & 3) * 8);
      const uint4 b1 = *(const uint4*)(B + (bn + (c1 >> 2)) * (long)K + k0 + (c1 & 3) * 8);
      *(uint4*)(&sA[(c0 >> 2) * LDSW + (c0 & 3) * 8]) = a0;
      *(uint4*)(&sA[(c1 >> 2) * LDSW + (c1 & 3) * 8]) = a1;
      *(uint4*)(&sB[(c0 >> 2) * LDSW + (c0 & 3) * 8]) = b0;
      *(uint4*)(&sB[(c1 >> 2) * LDSW + (c1 & 3) * 8]) = b1;
    }
    __syncthreads();
    bf8_t af[4], bfv[4];
#pragma unroll
    for (int i = 0; i < 4; i++)
      af[i] = *(const bf8_t*)(&sA[(wm + i * 16 + rr) * LDSW + quad * 8]);
#pragma unroll
    for (int j = 0; j < 4; j++)
      bfv[j] = *(const bf8_t*)(&sB[(wn + j * 16 + rr) * LDSW + quad * 8]);
#pragma unroll
    for (int i = 0; i < 4; i++)
#pragma unroll
      for (int j = 0; j < 4; j++)
        acc[i][j] = MFMA16(af[i], bfv[j], acc[i][j]);
  }
#pragma unroll
  for (int i = 0; i < 4; i++)
#pragma unroll
    for (int j = 0; j < 4; j++)
#pragma unroll
      for (int rg = 0; rg < 4; rg++) {
        long m = bm + wm + i * 16 + quad * 4 + rg;
        long n = bn + wn + j * 16 + rr;
        long id = m * (long)N + n;
        float x = acc[i][j][rg];
        if (MODE == 0) ((float*)Cv)[id] = x;
        else if (MODE == 1) ((u16*)Cv)[id] = f2bf(x);
        else if (MODE == 2) ((u16*)Cv)[id] = f2bf(tanhf(x));
        else if (MODE == 3) ((u16*)Cv)[id] = f2bf(sigf(x));
        else {
          float* C = (float*)Cv;
          float vv = C[id];
          float sg = sigf(x + aux1[(int)n]);
          C[id] = vv + (aux0[id] - vv) * sg;
        }
      }
}

// ================== 256x256 8-phase pipelined GEMM (T2+T3+T4+T5) ==================
// C[M,N] = A[M,K] * B[N,K]^T. bf16 in, MODE 0 fp32 out / MODE 1 bf16 out.
// Requires: M%256==0, N%256==0, K%64==0, K>=128 (NT>=2).
// LDS: [buf][A/B][ksub][256 rows][32 k] bf16, 128 KiB. Half-slot = one [256][32]
// slab = contiguous 16KB, staged by 2 global_load_lds_dwordx4 per thread.
// Read swizzle: 16B-slot q XOR (row&3); staging pre-permutes the GLOBAL source
// octet so the LDS dest stays linear (G21 both-sides-or-neither).
// Stage schedule (2 K-tiles ahead): (t,ph1):Ak1(t+1) (t,ph2):Bk1(t+1)
//                                   (t,ph3):Ak0(t+2) (t,ph4):Bk0(t+2)
// vmcnt: ph2 end = 8 (last tile: 0); ph4 end = 8 (t==NT-2: 4). Never 0 in
// steady state -> loads stay in flight across barriers (T4).
__device__ __forceinline__ void gload16(const u16* g, u16* l) {
  __builtin_amdgcn_global_load_lds((const __attribute__((address_space(1))) u32*)g,
                                   (__attribute__((address_space(3))) u32*)l, 16, 0, 0);
}

template <int MODE>
__global__ __launch_bounds__(512, 2) void gemm256_bt(
    const u16* __restrict__ A, const u16* __restrict__ Bw, void* __restrict__ Cv,
    int M, int N, int K, int rsp, long r0off, long r1off) {
  __shared__ u16 L[2][2][2][8192];
  const int tid = threadIdx.x;
  const int lane = tid & 63, w = tid >> 6;
  const int quad = lane >> 4, l15 = lane & 15;
  const long bm = (long)blockIdx.y * 256, bn = (long)blockIdx.x * 256;
  const int wm = (w >> 2) * 128, wn = (w & 3) * 64;
  const int NT = K >> 6;

  // staging map: unit u -> (row u>>2, 16B-slot u&3); source octet = slot ^ (row&3)
  const int u0 = tid, u1 = tid + 512;
  const int ar0 = u0 >> 2, ar1 = u1 >> 2;
  const int aq0 = (u0 & 3) ^ (ar0 & 3), aq1 = (u1 & 3) ^ (ar1 & 3);
  const u16* gA0 = A + (bm + ar0) * (long)K + aq0 * 8;
  const u16* gA1 = A + (bm + ar1) * (long)K + aq1 * 8;
  const u16* gB0 = Bw + (bn + ar0) * (long)K + aq0 * 8;
  const u16* gB1 = Bw + (bn + ar1) * (long)K + aq1 * 8;

  // frag read offsets (u16 units inside one [256][32] slot), XOR-swizzled.
  // row&3 == l15&3 for every fragment row (wm/wn/i*16/j*16 all ≡ 0 mod 4).
  const int qx = (quad ^ (l15 & 3)) * 8;
  const int roA = (wm + l15) * 32 + qx;
  const int roB = (wn + l15) * 32 + qx;

  f4_t acc[8][4];
#pragma unroll
  for (int i = 0; i < 8; i++)
#pragma unroll
    for (int j = 0; j < 4; j++) acc[i][j] = (f4_t){0.f, 0.f, 0.f, 0.f};

#define STG_A(buf, s, tt)                                   \
  {                                                         \
    long ko = ((long)(tt) << 6) + ((s) << 5);               \
    gload16(gA0 + ko, &L[buf][0][s][u0 * 8]);               \
    gload16(gA1 + ko, &L[buf][0][s][u1 * 8]);               \
  }
#define STG_B(buf, s, tt)                                   \
  {                                                         \
    long ko = ((long)(tt) << 6) + ((s) << 5);               \
    gload16(gB0 + ko, &L[buf][1][s][u0 * 8]);               \
    gload16(gB1 + ko, &L[buf][1][s][u1 * 8]);               \
  }
#define LDA4(P, o)                                          \
  _Pragma("unroll") for (int i = 0; i < 4; i++)             \
      aF[i] = *(const bf8_t*)((P) + roA + ((o) + i) * 512);
#define LDB4(P)                                             \
  _Pragma("unroll") for (int j = 0; j < 4; j++)             \
      bF[j] = *(const bf8_t*)((P) + roB + j * 512);
#define MFMA_BLK(base)                                      \
  __builtin_amdgcn_s_setprio(1);                            \
  _Pragma("unroll") for (int i = 0; i < 4; i++)             \
      _Pragma("unroll") for (int j = 0; j < 4; j++)         \
          acc[(base) + i][j] = MFMA16(aF[i], bF[j], acc[(base) + i][j]); \
  __builtin_amdgcn_s_setprio(0);
#define SBAR __builtin_amdgcn_s_barrier()

  // prologue: Ak0(0) Bk0(0) Ak1(0) Bk1(0) Ak0(1) Bk0(1); oldest 4 = tile0 ksub0
  STG_A(0, 0, 0); STG_B(0, 0, 0);
  STG_A(0, 1, 0); STG_B(0, 1, 0);
  if (NT > 1) { STG_A(1, 0, 1); STG_B(1, 0, 1); }
  asm volatile("s_waitcnt vmcnt(8)" ::: "memory");
  SBAR;

  bf8_t aF[4], bF[4];
  for (int t = 0; t < NT; ++t) {
    const int buf = t & 1;
    const u16* A0 = &L[buf][0][0][0];
    const u16* B0 = &L[buf][1][0][0];
    const u16* A1 = &L[buf][0][1][0];
    const u16* B1 = &L[buf][1][1][0];
    // ---- phase 1: ksub0, m0-3 ----
    LDA4(A0, 0);
    LDB4(B0);
    if (t + 1 < NT) STG_A(buf ^ 1, 1, t + 1);
    SBAR;
    asm volatile("s_waitcnt lgkmcnt(0)" ::: "memory");
    MFMA_BLK(0);
    SBAR;
    // ---- phase 2: ksub0, m4-7 (bF reused) ----
    LDA4(A0, 4);
    if (t + 1 < NT) STG_B(buf ^ 1, 1, t + 1);
    SBAR;
    asm volatile("s_waitcnt lgkmcnt(0)" ::: "memory");
    MFMA_BLK(4);
    if (t == NT - 1) asm volatile("s_waitcnt vmcnt(0)" ::: "memory");
    else asm volatile("s_waitcnt vmcnt(8)" ::: "memory");
    SBAR;
    // ---- phase 3: ksub1, m0-3 ----
    LDA4(A1, 0);
    LDB4(B1);
    if (t + 2 < NT) STG_A(buf, 0, t + 2);
    SBAR;
    asm volatile("s_waitcnt lgkmcnt(0)" ::: "memory");
    MFMA_BLK(0);
    SBAR;
    // ---- phase 4: ksub1, m4-7 ----
    LDA4(A1, 4);
    if (t + 2 < NT) STG_B(buf, 0, t + 2);
    SBAR;
    asm volatile("s_waitcnt lgkmcnt(0)" ::: "memory");
    MFMA_BLK(4);
    if (t == NT - 2) asm volatile("s_waitcnt vmcnt(4)" ::: "memory");
    else if (t < NT - 2) asm volatile("s_waitcnt vmcnt(8)" ::: "memory");
    SBAR;
  }

  // epilogue: row-remap supports folding the per-batch output projection
#pragma unroll
  for (int i = 0; i < 8; i++) {
#pragma unroll
    for (int rg = 0; rg < 4; rg++) {
      long mm = bm + wm + i * 16 + quad * 4 + rg;
      long crow = (mm < rsp) ? (mm + r0off) : (mm + r1off);
#pragma unroll
      for (int j = 0; j < 4; j++) {
        long n = bn + wn + j * 16 + l15;
        float x = acc[i][j][rg];
        if (MODE == 0) ((float*)Cv)[crow * (long)N + n] = x;
        else ((u16*)Cv)[crow * (long)N + n] = f2bf(x);
      }
    }
  }
#undef STG_A
#undef STG_B
#undef LDA4
#undef LDB4
#undef MFMA_BLK
#undef SBAR
}

// ---------------- post-GEMM elementwise ----------------
__global__ __launch_bounds__(256) void post1_kernel(
    const float* __restrict__ F1, const float* __restrict__ F4, float* F0,
    const float* __restrict__ F2,
    u16* __restrict__ KM, u16* __restrict__ KK, u16* __restrict__ BB, u16* __restrict__ VB,
    const float* __restrict__ k_k, const float* __restrict__ k_a,
    const float* __restrict__ wb, const float* __restrict__ ab) {
  const int lane = threadIdx.x & 63;
  const long th = (((long)blockIdx.x * 256) + threadIdx.x) >> 6;
  const int hcol = (int)(th & 31) * 64 + lane;
  const long idx = th * 64 + lane;
  float kraw = F1[idx];
  float kk0 = kraw * k_k[hcol];
  float ss = kk0 * kk0;
#pragma unroll
  for (int m = 32; m; m >>= 1) ss += __shfl_xor(ss, m, 64);
  float kkn = kk0 / fmaxf(sqrtf(ss), 1e-12f);
  float av = sigf(F4[idx] + ab[hcol]);
  float w = -0.6065306597126334f * sigf(F0[idx] + wb[hcol]);
  F0[idx] = w;
  KM[idx] = f2bf(kraw * (1.f + (av - 1.f) * k_a[hcol]));
  KK[idx] = f2bf(kkn);
  BB[idx] = f2bf(kkn * av);
  VB[idx] = f2bf(F2[idx]);
}

// ================= chunked RWKV7 scan (L=16) =================
constexpr int ST64 = 72;   // u16 stride for [16][64]
constexpr int ST32 = 40;   // u16 stride for [.][32]
constexpr int STX = 132;   // fp32 stride for X [16][128]

__global__ __launch_bounds__(64) void phaseA_kernel(
    const float* __restrict__ wS, const u16* __restrict__ kmS, const u16* __restrict__ kkS,
    const u16* __restrict__ bbS, const u16* __restrict__ vbS, const u16* __restrict__ rbS,
    float* __restrict__ POWb, u16* __restrict__ PAb, float* __restrict__ Zb,
    u16* __restrict__ GTb, float* __restrict__ CLb, int Tc, int sp0) {
  __shared__ u16 lXa[16 * ST64], lXr[16 * ST64], lYa[16 * ST64], lYb[16 * ST64];
  __shared__ u16 lYaT[64 * ST32], lYbT[64 * ST32], lVmT[64 * ST32];
  __shared__ u16 lTWt[64 * ST32], lTAt[64 * ST32];
  __shared__ u16 lP[16 * ST32], lQ[16 * ST32], lBm[16 * ST32];
  __shared__ float lA[16 * 16];
  __shared__ float lX[16 * STX];
  __shared__ float lcl[64];
  const int lane = threadIdx.x;
  const int quad = lane >> 4, l15 = lane & 15;
  const long tile = blockIdx.x;
  const int bh = (int)(tile & 63);
  const int col = (int)(tile >> 6);
  const int b = bh >> 5, h = bh & 31;
  const long s = tile;
  const f4_t z4 = {0.f, 0.f, 0.f, 0.f};

  {
    u32* p0 = (u32*)&lYaT[lane * ST32 + 16];
    u32* p1 = (u32*)&lYbT[lane * ST32 + 16];
    u32* p2 = (u32*)&lVmT[lane * ST32 + 16];
    u32* p3 = (u32*)&lTWt[lane * ST32 + 16];
    u32* p4 = (u32*)&lTAt[lane * ST32 + 16];
#pragma unroll
    for (int q = 0; q < 8; q++) { p0[q] = 0; p1[q] = 0; p2[q] = 0; p3[q] = 0; p4[q] = 0; }
    if (lane < 16) {
      u32* q0 = (u32*)&lP[lane * ST32 + 16];
      u32* q1 = (u32*)&lQ[lane * ST32 + 16];
      u32* q2 = (u32*)&lBm[lane * ST32 + 16];
#pragma unroll
      for (int q = 0; q < 8; q++) { q0[q] = 0; q1[q] = 0; q2[q] = 0; }
    }
  }

  const long rowbase = (long)b * Tc + (long)(sp0 + col) * 16;
  const long gbase = rowbase * 2048 + (long)h * 64 + lane;
  float cw = 0.f;
#pragma unroll
  for (int i = 0; i < 16; i++) {
    long g = gbase + (long)i * 2048;
    float w = wS[g];
    float km = bf2f(kmS[g]), kk = bf2f(kkS[g]), bb = bf2f(bbS[g]);
    float vv = bf2f(vbS[g]), rr2 = bf2f(rbS[g]);
    float cwm = cw;
    cw += w;
    float E1 = __expf(cwm), E2 = __expf(-cw), E3 = __expf(cw);
    float xa = -kk * E1;
    lXa[i * ST64 + lane] = f2bf(xa);
    lX[i * STX + 64 + lane] = xa;
    lXr[i * ST64 + lane] = f2bf(rr2 * E3);
    float ya = bb * E2, yb = km * E2;
    lYa[i * ST64 + lane] = f2bf(ya);
    lYb[i * ST64 + lane] = f2bf(yb);
    lYaT[lane * ST32 + i] = f2bf(ya);
    lYbT[lane * ST32 + i] = f2bf(yb);
    lVmT[lane * ST32 + i] = f2bf(vv);
    if (i == 15) { lcl[lane] = E3; CLb[s * 64 + lane] = E3; }
  }
  __syncthreads();

  {
    f4_t aA = z4, aB = z4, aP = z4, aQ = z4;
#pragma unroll
    for (int kc = 0; kc < 2; kc++) {
      bf8_t xa = *(const bf8_t*)&lXa[l15 * ST64 + quad * 8 + 32 * kc];
      bf8_t xr = *(const bf8_t*)&lXr[l15 * ST64 + quad * 8 + 32 * kc];
      bf8_t ya = *(const bf8_t*)&lYa[l15 * ST64 + quad * 8 + 32 * kc];
      bf8_t yb = *(const bf8_t*)&lYb[l15 * ST64 + quad * 8 + 32 * kc];
      aA = MFMA16(xa, ya, aA);
      aB = MFMA16(xa, yb, aB);
      aP = MFMA16(xr, ya, aP);
      aQ = MFMA16(xr, yb, aQ);
    }
#pragma unroll
    for (int rg = 0; rg < 4; rg++) {
      int m = quad * 4 + rg;
      lA[m * 16 + l15] = (l15 < m) ? aA[rg] : 0.f;
      lBm[m * ST32 + l15] = (l15 < m) ? f2bf(aB[rg]) : (u16)0;
      lP[m * ST32 + l15] = (l15 <= m) ? f2bf(aP[rg]) : (u16)0;
      lQ[m * ST32 + l15] = (l15 <= m) ? f2bf(aQ[rg]) : (u16)0;
    }
  }
  __syncthreads();

#pragma unroll
  for (int nt = 0; nt < 4; nt++) {
    f4_t acc = z4;
    bf8_t a = *(const bf8_t*)&lBm[l15 * ST32 + quad * 8];
    bf8_t bb2 = *(const bf8_t*)&lVmT[(nt * 16 + l15) * ST32 + quad * 8];
    acc = MFMA16(a, bb2, acc);
#pragma unroll
    for (int rg = 0; rg < 4; rg++) lX[(quad * 4 + rg) * STX + nt * 16 + l15] = acc[rg];
  }
  __syncthreads();

  for (int i = 1; i < 16; i++) {
    float x0 = lX[i * STX + lane], x1 = lX[i * STX + 64 + lane];
    for (int j = 0; j < i; j++) {
      float aij = lA[i * 16 + j];
      x0 += aij * lX[j * STX + lane];
      x1 += aij * lX[j * STX + 64 + lane];
    }
    lX[i * STX + lane] = x0;
    lX[i * STX + 64 + lane] = x1;
  }
#pragma unroll
  for (int i = 0; i < 16; i++) {
    lTWt[lane * ST32 + i] = f2bf(lX[i * STX + lane]);
    lTAt[lane * ST32 + i] = f2bf(lX[i * STX + 64 + lane]);
  }
  __syncthreads();

#pragma unroll
  for (int nt = 0; nt < 4; nt++) {
    f4_t acc = z4;
    bf8_t p = *(const bf8_t*)&lP[l15 * ST32 + quad * 8];
    bf8_t q = *(const bf8_t*)&lQ[l15 * ST32 + quad * 8];
    bf8_t tw = *(const bf8_t*)&lTWt[(nt * 16 + l15) * ST32 + quad * 8];
    bf8_t vm = *(const bf8_t*)&lVmT[(nt * 16 + l15) * ST32 + quad * 8];
    acc = MFMA16(p, tw, acc);
    acc = MFMA16(q, vm, acc);
#pragma unroll
    for (int rg = 0; rg < 4; rg++)
      POWb[s * 1024 + (quad * 4 + rg) * 64 + nt * 16 + l15] = acc[rg];
  }
#pragma unroll
  for (int nt = 0; nt < 4; nt++) {
    f4_t acc = z4;
    bf8_t p = *(const bf8_t*)&lP[l15 * ST32 + quad * 8];
    bf8_t ta = *(const bf8_t*)&lTAt[(nt * 16 + l15) * ST32 + quad * 8];
    acc = MFMA16(p, ta, acc);
#pragma unroll
    for (int rg = 0; rg < 4; rg++) {
      float xr = bf2f(lXr[(quad * 4 + rg) * ST64 + nt * 16 + l15]);
      PAb[s * 1024 + (quad * 4 + rg) * 64 + nt * 16 + l15] = f2bf(acc[rg] + xr);
    }
  }

#pragma unroll
  for (int mt = 0; mt < 4; mt++)
#pragma unroll
    for (int nt = 0; nt < 4; nt++) {
      f4_t acc = z4;
      bf8_t tw = *(const bf8_t*)&lTWt[(mt * 16 + l15) * ST32 + quad * 8];
      bf8_t vm = *(const bf8_t*)&lVmT[(mt * 16 + l15) * ST32 + quad * 8];
      bf8_t yat = *(const bf8_t*)&lYaT[(nt * 16 + l15) * ST32 + quad * 8];
      bf8_t ybt = *(const bf8_t*)&lYbT[(nt * 16 + l15) * ST32 + quad * 8];
      acc = MFMA16(tw, yat, acc);
      acc = MFMA16(vm, ybt, acc);
      float cl = lcl[nt * 16 + l15];
#pragma unroll
      for (int rg = 0; rg < 4; rg++)
        Zb[s * 4096 + (mt * 16 + quad * 4 + rg) * 64 + nt * 16 + l15] = acc[rg] * cl;
    }
#pragma unroll
  for (int mt = 0; mt < 4; mt++)
#pragma unroll
    for (int nt = 0; nt < 4; nt++) {
      f4_t acc = z4;
      bf8_t yat = *(const bf8_t*)&lYaT[(mt * 16 + l15) * ST32 + quad * 8];
      bf8_t ta = *(const bf8_t*)&lTAt[(nt * 16 + l15) * ST32 + quad * 8];
      acc = MFMA16(yat, ta, acc);
#pragma unroll
      for (int rg = 0; rg < 4; rg++) {
        float cl = lcl[mt * 16 + quad * 4 + rg];
        GTb[s * 4096 + (mt * 16 + quad * 4 + rg) * 64 + nt * 16 + l15] = f2bf(acc[rg] * cl);
      }
    }
}

// phase B: sequential state propagation per (b,h). S_new = S*cl + Sbf*G + Z.
__global__ __launch_bounds__(256) void phaseB_kernel(
    const float* __restrict__ Zb, const u16* __restrict__ GTb, const float* __restrict__ CLb,
    u16* __restrict__ S0b, float* __restrict__ state, int CT, int init) {
  __shared__ u16 Sb[64 * ST64];
  const int bh = blockIdx.x;
  const int tid = threadIdx.x, wv = tid >> 6, lane = tid & 63;
  const int quad = lane >> 4, l15 = lane & 15;
  float S[4][4];
  if (init) {
#pragma unroll
    for (int nt = 0; nt < 4; nt++)
#pragma unroll
      for (int rg = 0; rg < 4; rg++) S[nt][rg] = 0.f;
  } else {
#pragma unroll
    for (int nt = 0; nt < 4; nt++)
#pragma unroll
      for (int rg = 0; rg < 4; rg++)
        S[nt][rg] = state[(long)bh * 4096 + (16 * wv + quad * 4 + rg) * 64 + nt * 16 + l15];
  }
  const f4_t z4 = {0.f, 0.f, 0.f, 0.f};
  for (int c = 0; c < CT; c++) {
    long s = (long)c * 64 + bh;
#pragma unroll
    for (int nt = 0; nt < 4; nt++)
#pragma unroll
      for (int rg = 0; rg < 4; rg++)
        Sb[(16 * wv + quad * 4 + rg) * ST64 + nt * 16 + l15] = f2bf(S[nt][rg]);
    __syncthreads();
    f4_t acc[4] = {z4, z4, z4, z4};
#pragma unroll
    for (int kc = 0; kc < 2; kc++) {
      bf8_t a = *(const bf8_t*)&Sb[(16 * wv + l15) * ST64 + quad * 8 + 32 * kc];
      *(uint4*)(S0b + s * 4096 + (16 * wv + l15) * 64 + quad * 8 + 32 * kc) = *(uint4*)&a;
#pragma unroll
      for (int nt = 0; nt < 4; nt++) {
        bf8_t g = *(const bf8_t*)(GTb + s * 4096 + (nt * 16 + l15) * 64 + quad * 8 + 32 * kc);
        acc[nt] = MFMA16(a, g, acc[nt]);
      }
    }
#pragma unroll
    for (int nt = 0; nt < 4; nt++) {
      float cl = CLb[s * 64 + nt * 16 + l15];
#pragma unroll
      for (int rg = 0; rg < 4; rg++) {
        float z = Zb[s * 4096 + (16 * wv + quad * 4 + rg) * 64 + nt * 16 + l15];
        S[nt][rg] = S[nt][rg] * cl + acc[nt][rg] + z;
      }
    }
    __syncthreads();
  }
#pragma unroll
  for (int nt = 0; nt < 4; nt++)
#pragma unroll
    for (int rg = 0; rg < 4; rg++)
      state[(long)bh * 4096 + (16 * wv + quad * 4 + rg) * 64 + nt * 16 + l15] = S[nt][rg];
}

// phase C: O = POW + PA * S0^T
__global__ __launch_bounds__(64) void phaseC_kernel(
    const float* __restrict__ POWb, const u16* __restrict__ PAb, const u16* __restrict__ S0b,
    float* __restrict__ O, int Tc, int sp0) {
  const int lane = threadIdx.x, quad = lane >> 4, l15 = lane & 15;
  const long tile = blockIdx.x;
  const int bh = (int)(tile & 63), col = (int)(tile >> 6);
  const int b = bh >> 5, h = bh & 31;
  const long s = tile;
  const f4_t z4 = {0.f, 0.f, 0.f, 0.f};
  f4_t acc[4] = {z4, z4, z4, z4};
#pragma unroll
  for (int kc = 0; kc < 2; kc++) {
    bf8_t a = *(const bf8_t*)(PAb + s * 1024 + l15 * 64 + quad * 8 + 32 * kc);
#pragma unroll
    for (int nt = 0; nt < 4; nt++) {
      bf8_t bo = *(const bf8_t*)(S0b + s * 4096 + (nt * 16 + l15) * 64 + quad * 8 + 32 * kc);
      acc[nt] = MFMA16(a, bo, acc[nt]);
    }
  }
  const long rowbase = (long)b * Tc + (long)(sp0 + col) * 16;
#pragma unroll
  for (int nt = 0; nt < 4; nt++)
#pragma unroll
    for (int rg = 0; rg < 4; rg++) {
      int i = quad * 4 + rg, v = nt * 16 + l15;
      float p = POWb[s * 1024 + i * 64 + v];
      O[(rowbase + i) * 2048 + (long)h * 64 + v] = p + acc[nt][rg];
    }
}

// ---------------- group-norm + residual + gate ----------------
__global__ __launch_bounds__(256) void epi_kernel(
    const float* __restrict__ o, const u16* __restrict__ r, const u16* __restrict__ k,
    const u16* __restrict__ v, const u16* __restrict__ g,
    const float* __restrict__ r_k, const float* __restrict__ gn_w, const float* __restrict__ gn_b,
    u16* __restrict__ y) {
  const int lane = threadIdx.x & 63;
  const long th = (((long)blockIdx.x * 256) + threadIdx.x) >> 6;
  const int hcol = (int)(th & 31) * 64 + lane;
  const long idx = th * 64 + lane;
  float ov = o[idx];
  float s = ov;
#pragma unroll
  for (int m = 32; m; m >>= 1) s += __shfl_xor(s, m, 64);
  float mu = s * (1.f / 64.f);
  float d = ov - mu;
  float vs = d * d;
#pragma unroll
  for (int m = 32; m; m >>= 1) vs += __shfl_xor(vs, m, 64);
  float on = d * rsqrtf(vs * (1.f / 64.f) + 6.4e-4f);
  on = on * gn_w[hcol] + gn_b[hcol];
  float rk = bf2f(r[idx]) * bf2f(k[idx]) * r_k[hcol];
#pragma unroll
  for (int m = 32; m; m >>= 1) rk += __shfl_xor(rk, m, 64);
  on += rk * bf2f(v[idx]);
  y[idx] = f2bf(on * bf2f(g[idx]));
}

// =============================== host ===============================
extern "C" void kernel_launch(void* const* d_in, const int* in_sizes, int n_in,
                              void* d_out, int out_size, void* d_ws, size_t ws_size,
                              hipStream_t stream) {
  constexpr int B = 2, T = 4096, H = 2048;
  const float* hst    = (const float*)d_in[0];
  const float* vfirst = (const float*)d_in[1];
  const float* x_r = (const float*)d_in[2];
  const float* x_w = (const float*)d_in[3];
  const float* x_k = (const float*)d_in[4];
  const float* x_v = (const float*)d_in[5];
  const float* x_a = (const float*)d_in[6];
  const float* x_g = (const float*)d_in[7];
  const float* k_k = (const float*)d_in[8];
  const float* k_a = (const float*)d_in[9];
  const float* r_k = (const float*)d_in[10];
  const float* w_r = (const float*)d_in[11];
  const float* w_k = (const float*)d_in[12];
  const float* w_v = (const float*)d_in[13];
  const float* w_o = (const float*)d_in[14];
  const float* wA  = (const float*)d_in[15];
  const float* wB  = (const float*)d_in[16];
  const float* wb  = (const float*)d_in[17];
  const float* aA  = (const float*)d_in[18];
  const float* aB  = (const float*)d_in[19];
  const float* ab  = (const float*)d_in[20];
  const float* vA  = (const float*)d_in[21];
  const float* vB  = (const float*)d_in[22];
  const float* vb  = (const float*)d_in[23];
  const float* gA  = (const float*)d_in[24];
  const float* gB  = (const float*)d_in[25];
  const float* gn_w= (const float*)d_in[26];
  const float* gn_b= (const float*)d_in[27];

  const size_t WEIGHT_BYTES = 4 * (size_t)H * H * 2 + 6 * (size_t)128 * H * 2
                            + 2 * (size_t)256 * H * 2;
  const size_t STATE_BYTES = (size_t)64 * 4096 * 4;
  const size_t TILE_BYTES = 4096 + 2048 + 16384 + 8192 + 256 + 8192;  // POW PA Z GT CL S0

  int NC = -1, CT = 0;
  for (int pass = 0; pass < 2 && NC < 0; pass++) {
    for (int nc : {1, 2, 4, 8, 16}) {
      long Tc_ = T / nc;
      long R_ = (long)B * Tc_;
      long RH_ = R_ * H;
      size_t base = (size_t)RH_ * 16 + (size_t)RH_ * 10 + (size_t)RH_ * 4 + (size_t)R_ * 512
                  + WEIGHT_BYTES + STATE_BYTES + (1 << 20);
      int cols = (int)(Tc_ / 16);
      int found = 0;
      for (int ct : {64, 32, 16, 8}) {
        if (ct > cols) continue;
        if (pass == 0 && ct < 16) continue;
        size_t need = base + (size_t)64 * ct * TILE_BYTES;
        if (need <= ws_size) { NC = nc; CT = ct; found = 1; break; }
      }
      if (found) break;
    }
  }
  const int BS = 256;
  auto cdiv = [](long a, long b) { return (int)((a + b - 1) / b); };
  if (NC < 0) {
    fill_kernel<<<cdiv(out_size, BS), BS, 0, stream>>>(
        (float*)d_out, 200000.f + (float)(ws_size >> 20), out_size);
    return;
  }
  const int Tc = T / NC;
  const long R = (long)B * Tc;
  const long RH = R * H;
  const int cols = Tc / 16;
  const int NTILE = 64 * CT;

  char* ws = (char*)d_ws;
  size_t off = 0;
  auto alloc = [&](size_t bytes) -> void* {
    void* p = ws + off;
    off += (bytes + 255) & ~(size_t)255;
    return p;
  };
  float* F0 = (float*)alloc(RH * 4);
  float* F1 = (float*)alloc(RH * 4);
  float* F2 = (float*)alloc(RH * 4);
  float* F4 = (float*)alloc(RH * 4);
  u16* KM  = (u16*)alloc(RH * 2);
  u16* KK  = (u16*)alloc(RH * 2);
  u16* BBs = (u16*)alloc(RH * 2);
  u16* VBs = (u16*)alloc(RH * 2);
  u16* RBs = (u16*)alloc(RH * 2);
  u16* MIXB = (u16*)alloc(RH * 2);
  u16* G    = (u16*)alloc(RH * 2);
  u16* s1b  = (u16*)alloc(R * 512);
  u16* wrb = (u16*)alloc((size_t)H * H * 2);
  u16* wkb = (u16*)alloc((size_t)H * H * 2);
  u16* wvb = (u16*)alloc((size_t)H * H * 2);
  u16* wob = (u16*)alloc((size_t)H * H * 2);
  u16* wAb = (u16*)alloc((size_t)128 * H * 2);
  u16* wBb = (u16*)alloc((size_t)H * 128 * 2);
  u16* aAb = (u16*)alloc((size_t)128 * H * 2);
  u16* aBb = (u16*)alloc((size_t)H * 128 * 2);
  u16* vAb = (u16*)alloc((size_t)128 * H * 2);
  u16* vBb = (u16*)alloc((size_t)H * 128 * 2);
  u16* gAb = (u16*)alloc((size_t)256 * H * 2);
  u16* gBb = (u16*)alloc((size_t)H * 256 * 2);
  float* state = (float*)alloc(STATE_BYTES);
  float* POWb = (float*)alloc((size_t)NTILE * 4096);
  u16*   PAb  = (u16*)alloc((size_t)NTILE * 2048);
  float* Zb   = (float*)alloc((size_t)NTILE * 16384);
  u16*   GTb  = (u16*)alloc((size_t)NTILE * 8192);
  float* CLb  = (float*)alloc((size_t)NTILE * 256);
  u16*   S0b  = (u16*)alloc((size_t)NTILE * 8192);
  float* Ob = F1;

  padcvt_kernel<<<cdiv((long)H * H, BS), BS, 0, stream>>>(w_r, wrb, H, H, H, (long)H * H);
  padcvt_kernel<<<cdiv((long)H * H, BS), BS, 0, stream>>>(w_k, wkb, H, H, H, (long)H * H);
  padcvt_kernel<<<cdiv((long)H * H, BS), BS, 0, stream>>>(w_v, wvb, H, H, H, (long)H * H);
  padcvt_kernel<<<cdiv((long)H * H, BS), BS, 0, stream>>>(w_o, wob, H, H, H, (long)H * H);
  padcvt_kernel<<<cdiv((long)128 * H, BS), BS, 0, stream>>>(wA, wAb, 96, H, H, (long)128 * H);
  padcvt_kernel<<<cdiv((long)H * 128, BS), BS, 0, stream>>>(wB, wBb, H, 96, 128, (long)H * 128);
  padcvt_kernel<<<cdiv((long)128 * H, BS), BS, 0, stream>>>(aA, aAb, 96, H, H, (long)128 * H);
  padcvt_kernel<<<cdiv((long)H * 128, BS), BS, 0, stream>>>(aB, aBb, H, 96, 128, (long)H * 128);
  padcvt_kernel<<<cdiv((long)128 * H, BS), BS, 0, stream>>>(vA, vAb, 64, H, H, (long)128 * H);
  padcvt_kernel<<<cdiv((long)H * 128, BS), BS, 0, stream>>>(vB, vBb, H, 64, 128, (long)H * 128);
  padcvt_kernel<<<cdiv((long)256 * H, BS), BS, 0, stream>>>(gA, gAb, 256, H, H, (long)256 * H);
  padcvt_kernel<<<cdiv((long)H * 256, BS), BS, 0, stream>>>(gB, gBb, H, 256, 256, (long)H * 256);

  const long mixTot = (long)Tc * H / 4;
  const int mixG = cdiv(mixTot, BS);
  const int ehG = (int)(R * 32 / 4);

  for (int c = 0; c < NC; c++) {
    const int t0 = c * Tc;
    auto MIX = [&](const float* coef) {
      for (int b = 0; b < B; b++)
        mix1_kernel<<<mixG, BS, 0, stream>>>(hst + (long)b * T * H, coef,
                                             MIXB + (long)b * Tc * H, t0, Tc, mixTot);
    };
    dim3 gN128(1, (unsigned)(R / 128)), gN256(2, (unsigned)(R / 128));
    dim3 g256((unsigned)(H / 256), (unsigned)(R / 256));
    // w-lora -> F0 (w-logit)
    MIX(x_w);
    gemm_bt<2><<<gN128, 256, 0, stream>>>(MIXB, wAb, s1b, (int)R, 128, H, nullptr, nullptr);
    gemm256_bt<0><<<g256, 512, 0, stream>>>(s1b, wBb, F0, (int)R, H, 128, (int)R, 0, 0);
    // a-lora -> F4
    MIX(x_a);
    gemm_bt<1><<<gN128, 256, 0, stream>>>(MIXB, aAb, s1b, (int)R, 128, H, nullptr, nullptr);
    gemm256_bt<0><<<g256, 512, 0, stream>>>(s1b, aBb, F4, (int)R, H, 128, (int)R, 0, 0);
    // v: raw proj + lerp
    MIX(x_v);
    gemm256_bt<0><<<g256, 512, 0, stream>>>(MIXB, wvb, F2, (int)R, H, H, (int)R, 0, 0);
    gemm_bt<1><<<gN128, 256, 0, stream>>>(MIXB, vAb, s1b, (int)R, 128, H, nullptr, nullptr);
    for (int b = 0; b < B; b++) {
      dim3 gHalf(16, (unsigned)(Tc / 128));
      gemm_bt<4><<<gHalf, 256, 0, stream>>>(s1b + (long)b * Tc * 128, vBb,
                                            F2 + (long)b * Tc * H, Tc, H, 128,
                                            vfirst + ((long)b * T + t0) * H, vb);
    }
    // g-lora -> G
    MIX(x_g);
    gemm_bt<3><<<gN256, 256, 0, stream>>>(MIXB, gAb, s1b, (int)R, 256, H, nullptr, nullptr);
    gemm256_bt<1><<<g256, 512, 0, stream>>>(s1b, gBb, G, (int)R, H, 256, (int)R, 0, 0);
    // r -> RBs (bf16), k -> F1 (fp32)
    MIX(x_r);
    gemm256_bt<1><<<g256, 512, 0, stream>>>(MIXB, wrb, RBs, (int)R, H, H, (int)R, 0, 0);
    MIX(x_k);
    gemm256_bt<0><<<g256, 512, 0, stream>>>(MIXB, wkb, F1, (int)R, H, H, (int)R, 0, 0);
    // elementwise
    post1_kernel<<<ehG, 256, 0, stream>>>(F1, F4, F0, F2, KM, KK, BBs, VBs,
                                          k_k, k_a, wb, ab);
    // chunked scan
    for (int sp = 0; sp < cols; sp += CT) {
      phaseA_kernel<<<NTILE, 64, 0, stream>>>(F0, KM, KK, BBs, VBs, RBs,
                                              POWb, PAb, Zb, GTb, CLb, Tc, sp);
      phaseB_kernel<<<64, 256, 0, stream>>>(Zb, GTb, CLb, S0b, state, CT,
                                            (c == 0 && sp == 0) ? 1 : 0);
      phaseC_kernel<<<NTILE, 64, 0, stream>>>(POWb, PAb, S0b, Ob, Tc, sp);
    }
    // groupnorm + residual + gate -> MIXB
    epi_kernel<<<ehG, 256, 0, stream>>>(Ob, RBs, KM, VBs, G, r_k, gn_w, gn_b, MIXB);
    // output projection: single full-grid dispatch, row-remap folds the b-loop
    gemm256_bt<0><<<g256, 512, 0, stream>>>(MIXB, wob, (float*)d_out, (int)R, H, H,
                                            Tc, (long)t0, (long)T - Tc + t0);
  }
}

// Round 3
// 3086.545 us; speedup vs baseline: 1.2420x; 1.2420x over previous
//
#include <hip/hip_runtime.h>
#include <cstdint>
#include <cstddef>

typedef unsigned short u16;
typedef unsigned int u32;

typedef __bf16 bf8_t __attribute__((ext_vector_type(8)));
typedef float f4_t __attribute__((ext_vector_type(4)));

__device__ __forceinline__ u16 f2bf(float x) {
  u32 u = __float_as_uint(x);
  u = (u + 0x7fffu + ((u >> 16) & 1u)) >> 16;
  return (u16)u;
}
__device__ __forceinline__ float bf2f(u16 x) {
  u32 u = ((u32)x) << 16;
  return __uint_as_float(u);
}
__device__ __forceinline__ float sigf(float x) { return 1.f / (1.f + __expf(-x)); }

#define MFMA16(a, b, c) __builtin_amdgcn_mfma_f32_16x16x32_bf16(a, b, c, 0, 0, 0)

// ---------------- fill (sentinel) ----------------
__global__ void fill_kernel(float* p, float v, long n) {
  long i = (long)blockIdx.x * blockDim.x + threadIdx.x;
  if (i < n) p[i] = v;
}

// ---------------- fp32 -> bf16 weight convert with zero padding ----------------
__global__ void padcvt_kernel(const float* __restrict__ src, u16* __restrict__ dst,
                              int rows, int cols, int pc, long total) {
  long i = (long)blockIdx.x * blockDim.x + threadIdx.x;
  if (i >= total) return;
  int r = (int)(i / pc), c = (int)(i % pc);
  float v = (r < rows && c < cols) ? src[(long)r * cols + c] : 0.f;
  dst[i] = f2bf(v);
}

// ---------------- fused stage1 weight stack: Wf[row0+r][k] ----------------
// k<2048: W[r][k] ; k>=2048: W[r][k-2048]*coef[k-2048] ; r>=rows_valid: 0
__global__ void wf_kernel(const float* __restrict__ src, const float* __restrict__ coef,
                          u16* __restrict__ Wf, int rows_valid, int row0, long total) {
  long i = (long)blockIdx.x * blockDim.x + threadIdx.x;
  if (i >= total) return;
  int r = (int)(i >> 12);          // /4096
  int k = (int)(i & 4095);
  float v = 0.f;
  if (r < rows_valid) {
    int kk = k & 2047;
    v = src[(long)r * 2048 + kk];
    if (k >= 2048) v *= coef[kk];
  }
  Wf[(long)(row0 + r) * 4096 + k] = f2bf(v);
}

// ---------------- HD = [h | delta] bf16 (per chunk) ----------------
__global__ void hd_kernel(const float* __restrict__ h_b, u16* __restrict__ out_seg,
                          int t0, int Tc, long total4) {
  long i = (long)blockIdx.x * blockDim.x + threadIdx.x;
  if (i >= total4) return;
  long e = i * 4;
  const int H = 2048;
  int col = (int)(e % H);
  int tl = (int)(e / H);
  int tg = t0 + tl;
  const float* hp = h_b + (long)tg * H + col;
  float4 hv = *(const float4*)hp;
  float4 pv = make_float4(0.f, 0.f, 0.f, 0.f);
  if (tg > 0) pv = *(const float4*)(hp - H);
  u16* row = out_seg + (long)tl * 4096;
  uint2 ph, pd;
  ph.x = (u32)f2bf(hv.x) | ((u32)f2bf(hv.y) << 16);
  ph.y = (u32)f2bf(hv.z) | ((u32)f2bf(hv.w) << 16);
  pd.x = (u32)f2bf(pv.x - hv.x) | ((u32)f2bf(pv.y - hv.y) << 16);
  pd.y = (u32)f2bf(pv.z - hv.z) | ((u32)f2bf(pv.w - hv.w) << 16);
  *(uint2*)(row + col) = ph;
  *(uint2*)(row + 2048 + col) = pd;
}

// ---------------- token-shift mix ----------------
__global__ void mix1_kernel(const float* __restrict__ h_b, const float* __restrict__ coef,
                            u16* __restrict__ out_seg, int t0, int Tc, long total4) {
  long i = (long)blockIdx.x * blockDim.x + threadIdx.x;
  if (i >= total4) return;
  long e = i * 4;
  const int H = 2048;
  int col = (int)(e % H);
  int tl = (int)(e / H);
  int tg = t0 + tl;
  const float* hp = h_b + (long)tg * H + col;
  float4 hv = *(const float4*)hp;
  float4 pv = make_float4(0.f, 0.f, 0.f, 0.f);
  if (tg > 0) pv = *(const float4*)(hp - H);
  float4 cc = *(const float4*)(coef + col);
  uint2 pk;
  pk.x = (u32)f2bf(hv.x + (pv.x - hv.x) * cc.x) | ((u32)f2bf(hv.y + (pv.y - hv.y) * cc.y) << 16);
  pk.y = (u32)f2bf(hv.z + (pv.z - hv.z) * cc.z) | ((u32)f2bf(hv.w + (pv.w - hv.w) * cc.w) << 16);
  *(uint2*)(out_seg + e) = pk;
}

// ---------------- bf16 MFMA GEMM (128x128) ----------------
// MODE 0: fp32. 1: bf16. 2: tanh->bf16. 3: sigmoid->bf16. 4: fp32 lerp epilogue.
// MODE 5: fused stage1 (col<128 tanh, col<384 plain, else sigmoid) -> bf16.
#define LDSW 40
template <int MODE>
__global__ __launch_bounds__(256) void gemm_bt(
    const u16* __restrict__ A, const u16* __restrict__ B, void* __restrict__ Cv,
    int M, int N, int K, int lda, const float* __restrict__ aux0, const float* __restrict__ aux1) {
  __shared__ u16 sA[128 * LDSW];
  __shared__ u16 sB[128 * LDSW];
  const int tid = threadIdx.x;
  const long bm = (long)blockIdx.y * 128;
  const long bn = (long)blockIdx.x * 128;
  const int wave = tid >> 6, lane = tid & 63;
  const int wm = (wave >> 1) * 64, wn = (wave & 1) * 64;
  const int quad = lane >> 4, rr = lane & 15;

  f4_t acc[4][4];
  const f4_t zero = {0.f, 0.f, 0.f, 0.f};
#pragma unroll
  for (int i = 0; i < 4; i++)
#pragma unroll
    for (int j = 0; j < 4; j++) acc[i][j] = zero;

  const int c0 = tid, c1 = tid + 256;
  for (int k0 = 0; k0 < K; k0 += 32) {
    __syncthreads();
    {
      const uint4 a0 = *(const uint4*)(A + (bm + (c0 >> 2)) * (long)lda + k0 + (c0 & 3) * 8);
      const uint4 a1 = *(const uint4*)(A + (bm + (c1 >> 2)) * (long)lda + k0 + (c1 & 3) * 8);
      const uint4 b0 = *(const uint4*)(B + (bn + (c0 >> 2)) * (long)K + k0 + (c0 & 3) * 8);
      const uint4 b1 = *(const uint4*)(B + (bn + (c1 >> 2)) * (long)K + k0 + (c1 & 3) * 8);
      *(uint4*)(&sA[(c0 >> 2) * LDSW + (c0 & 3) * 8]) = a0;
      *(uint4*)(&sA[(c1 >> 2) * LDSW + (c1 & 3) * 8]) = a1;
      *(uint4*)(&sB[(c0 >> 2) * LDSW + (c0 & 3) * 8]) = b0;
      *(uint4*)(&sB[(c1 >> 2) * LDSW + (c1 & 3) * 8]) = b1;
    }
    __syncthreads();
    bf8_t af[4], bfv[4];
#pragma unroll
    for (int i = 0; i < 4; i++)
      af[i] = *(const bf8_t*)(&sA[(wm + i * 16 + rr) * LDSW + quad * 8]);
#pragma unroll
    for (int j = 0; j < 4; j++)
      bfv[j] = *(const bf8_t*)(&sB[(wn + j * 16 + rr) * LDSW + quad * 8]);
#pragma unroll
    for (int i = 0; i < 4; i++)
#pragma unroll
      for (int j = 0; j < 4; j++)
        acc[i][j] = MFMA16(af[i], bfv[j], acc[i][j]);
  }
#pragma unroll
  for (int i = 0; i < 4; i++)
#pragma unroll
    for (int j = 0; j < 4; j++)
#pragma unroll
      for (int rg = 0; rg < 4; rg++) {
        long m = bm + wm + i * 16 + quad * 4 + rg;
        long n = bn + wn + j * 16 + rr;
        long id = m * (long)N + n;
        float x = acc[i][j][rg];
        if (MODE == 0) ((float*)Cv)[id] = x;
        else if (MODE == 1) ((u16*)Cv)[id] = f2bf(x);
        else if (MODE == 2) ((u16*)Cv)[id] = f2bf(tanhf(x));
        else if (MODE == 3) ((u16*)Cv)[id] = f2bf(sigf(x));
        else if (MODE == 5) {
          float y = (n < 128) ? tanhf(x) : ((n < 384) ? x : sigf(x));
          ((u16*)Cv)[id] = f2bf(y);
        } else {
          float* C = (float*)Cv;
          float vv = C[id];
          float sg = sigf(x + aux1[(int)n]);
          C[id] = vv + (aux0[id] - vv) * sg;
        }
      }
}

// ================== 256x256 8-phase pipelined GEMM (T2+T3+T4+T5) ==================
// C[M,N] = A[M,K] * B[N,K]^T. bf16 in, MODE 0 fp32 out / MODE 1 bf16 out.
// Used only for K>=2048 (deep pipeline amortizes prologue/drain).
__device__ __forceinline__ void gload16(const u16* g, u16* l) {
  __builtin_amdgcn_global_load_lds((const __attribute__((address_space(1))) u32*)g,
                                   (__attribute__((address_space(3))) u32*)l, 16, 0, 0);
}

template <int MODE>
__global__ __launch_bounds__(512, 2) void gemm256_bt(
    const u16* __restrict__ A, const u16* __restrict__ Bw, void* __restrict__ Cv,
    int M, int N, int K, int rsp, long r0off, long r1off) {
  __shared__ u16 L[2][2][2][8192];
  const int tid = threadIdx.x;
  const int lane = tid & 63, w = tid >> 6;
  const int quad = lane >> 4, l15 = lane & 15;
  const long bm = (long)blockIdx.y * 256, bn = (long)blockIdx.x * 256;
  const int wm = (w >> 2) * 128, wn = (w & 3) * 64;
  const int NT = K >> 6;

  const int u0 = tid, u1 = tid + 512;
  const int ar0 = u0 >> 2, ar1 = u1 >> 2;
  const int aq0 = (u0 & 3) ^ (ar0 & 3), aq1 = (u1 & 3) ^ (ar1 & 3);
  const u16* gA0 = A + (bm + ar0) * (long)K + aq0 * 8;
  const u16* gA1 = A + (bm + ar1) * (long)K + aq1 * 8;
  const u16* gB0 = Bw + (bn + ar0) * (long)K + aq0 * 8;
  const u16* gB1 = Bw + (bn + ar1) * (long)K + aq1 * 8;

  const int qx = (quad ^ (l15 & 3)) * 8;
  const int roA = (wm + l15) * 32 + qx;
  const int roB = (wn + l15) * 32 + qx;

  f4_t acc[8][4];
#pragma unroll
  for (int i = 0; i < 8; i++)
#pragma unroll
    for (int j = 0; j < 4; j++) acc[i][j] = (f4_t){0.f, 0.f, 0.f, 0.f};

#define STG_A(buf, s, tt)                                   \
  {                                                         \
    long ko = ((long)(tt) << 6) + ((s) << 5);               \
    gload16(gA0 + ko, &L[buf][0][s][u0 * 8]);               \
    gload16(gA1 + ko, &L[buf][0][s][u1 * 8]);               \
  }
#define STG_B(buf, s, tt)                                   \
  {                                                         \
    long ko = ((long)(tt) << 6) + ((s) << 5);               \
    gload16(gB0 + ko, &L[buf][1][s][u0 * 8]);               \
    gload16(gB1 + ko, &L[buf][1][s][u1 * 8]);               \
  }
#define LDA4(P, o)                                          \
  _Pragma("unroll") for (int i = 0; i < 4; i++)             \
      aF[i] = *(const bf8_t*)((P) + roA + ((o) + i) * 512);
#define LDB4(P)                                             \
  _Pragma("unroll") for (int j = 0; j < 4; j++)             \
      bF[j] = *(const bf8_t*)((P) + roB + j * 512);
#define MFMA_BLK(base)                                      \
  __builtin_amdgcn_s_setprio(1);                            \
  _Pragma("unroll") for (int i = 0; i < 4; i++)             \
      _Pragma("unroll") for (int j = 0; j < 4; j++)         \
          acc[(base) + i][j] = MFMA16(aF[i], bF[j], acc[(base) + i][j]); \
  __builtin_amdgcn_s_setprio(0);
#define SBAR __builtin_amdgcn_s_barrier()

  STG_A(0, 0, 0); STG_B(0, 0, 0);
  STG_A(0, 1, 0); STG_B(0, 1, 0);
  if (NT > 1) { STG_A(1, 0, 1); STG_B(1, 0, 1); }
  asm volatile("s_waitcnt vmcnt(8)" ::: "memory");
  SBAR;

  bf8_t aF[4], bF[4];
  for (int t = 0; t < NT; ++t) {
    const int buf = t & 1;
    const u16* A0 = &L[buf][0][0][0];
    const u16* B0 = &L[buf][1][0][0];
    const u16* A1 = &L[buf][0][1][0];
    const u16* B1 = &L[buf][1][1][0];
    // ---- phase 1 ----
    LDA4(A0, 0);
    LDB4(B0);
    if (t + 1 < NT) STG_A(buf ^ 1, 1, t + 1);
    SBAR;
    asm volatile("s_waitcnt lgkmcnt(0)" ::: "memory");
    MFMA_BLK(0);
    SBAR;
    // ---- phase 2 ----
    LDA4(A0, 4);
    if (t + 1 < NT) STG_B(buf ^ 1, 1, t + 1);
    SBAR;
    asm volatile("s_waitcnt lgkmcnt(0)" ::: "memory");
    MFMA_BLK(4);
    if (t == NT - 1) asm volatile("s_waitcnt vmcnt(0)" ::: "memory");
    else asm volatile("s_waitcnt vmcnt(8)" ::: "memory");
    SBAR;
    // ---- phase 3 ----
    LDA4(A1, 0);
    LDB4(B1);
    if (t + 2 < NT) STG_A(buf, 0, t + 2);
    SBAR;
    asm volatile("s_waitcnt lgkmcnt(0)" ::: "memory");
    MFMA_BLK(0);
    SBAR;
    // ---- phase 4 ----
    LDA4(A1, 4);
    if (t + 2 < NT) STG_B(buf, 0, t + 2);
    SBAR;
    asm volatile("s_waitcnt lgkmcnt(0)" ::: "memory");
    MFMA_BLK(4);
    if (t == NT - 2) asm volatile("s_waitcnt vmcnt(4)" ::: "memory");
    else if (t < NT - 2) asm volatile("s_waitcnt vmcnt(8)" ::: "memory");
    SBAR;
  }

#pragma unroll
  for (int i = 0; i < 8; i++) {
#pragma unroll
    for (int rg = 0; rg < 4; rg++) {
      long mm = bm + wm + i * 16 + quad * 4 + rg;
      long crow = (mm < rsp) ? (mm + r0off) : (mm + r1off);
#pragma unroll
      for (int j = 0; j < 4; j++) {
        long n = bn + wn + j * 16 + l15;
        float x = acc[i][j][rg];
        if (MODE == 0) ((float*)Cv)[crow * (long)N + n] = x;
        else ((u16*)Cv)[crow * (long)N + n] = f2bf(x);
      }
    }
  }
#undef STG_A
#undef STG_B
#undef LDA4
#undef LDB4
#undef MFMA_BLK
#undef SBAR
}

// ---------------- post-GEMM elementwise ----------------
__global__ __launch_bounds__(256) void post1_kernel(
    const float* __restrict__ F1, const float* __restrict__ F4, float* F0,
    const float* __restrict__ F2,
    u16* __restrict__ KM, u16* __restrict__ KK, u16* __restrict__ BB, u16* __restrict__ VB,
    const float* __restrict__ k_k, const float* __restrict__ k_a,
    const float* __restrict__ wb, const float* __restrict__ ab) {
  const int lane = threadIdx.x & 63;
  const long th = (((long)blockIdx.x * 256) + threadIdx.x) >> 6;
  const int hcol = (int)(th & 31) * 64 + lane;
  const long idx = th * 64 + lane;
  float kraw = F1[idx];
  float kk0 = kraw * k_k[hcol];
  float ss = kk0 * kk0;
#pragma unroll
  for (int m = 32; m; m >>= 1) ss += __shfl_xor(ss, m, 64);
  float kkn = kk0 / fmaxf(sqrtf(ss), 1e-12f);
  float av = sigf(F4[idx] + ab[hcol]);
  float w = -0.6065306597126334f * sigf(F0[idx] + wb[hcol]);
  F0[idx] = w;
  KM[idx] = f2bf(kraw * (1.f + (av - 1.f) * k_a[hcol]));
  KK[idx] = f2bf(kkn);
  BB[idx] = f2bf(kkn * av);
  VB[idx] = f2bf(F2[idx]);
}

// ================= chunked RWKV7 scan (L=16) =================
constexpr int ST64 = 72;   // u16 stride for [16][64]
constexpr int ST32 = 40;   // u16 stride for [.][32]
constexpr int STX = 132;   // fp32 stride for X [16][128]

__global__ __launch_bounds__(64) void phaseA_kernel(
    const float* __restrict__ wS, const u16* __restrict__ kmS, const u16* __restrict__ kkS,
    const u16* __restrict__ bbS, const u16* __restrict__ vbS, const u16* __restrict__ rbS,
    float* __restrict__ POWb, u16* __restrict__ PAb, float* __restrict__ Zb,
    u16* __restrict__ GTb, float* __restrict__ CLb, int Tc, int sp0) {
  __shared__ u16 lXa[16 * ST64], lXr[16 * ST64], lYa[16 * ST64], lYb[16 * ST64];
  __shared__ u16 lYaT[64 * ST32], lYbT[64 * ST32], lVmT[64 * ST32];
  __shared__ u16 lTWt[64 * ST32], lTAt[64 * ST32];
  __shared__ u16 lP[16 * ST32], lQ[16 * ST32], lBm[16 * ST32];
  __shared__ float lA[16 * 16];
  __shared__ float lX[16 * STX];
  __shared__ float lcl[64];
  const int lane = threadIdx.x;
  const int quad = lane >> 4, l15 = lane & 15;
  const long tile = blockIdx.x;
  const int bh = (int)(tile & 63);
  const int col = (int)(tile >> 6);
  const int b = bh >> 5, h = bh & 31;
  const long s = tile;
  const f4_t z4 = {0.f, 0.f, 0.f, 0.f};

  {
    u32* p0 = (u32*)&lYaT[lane * ST32 + 16];
    u32* p1 = (u32*)&lYbT[lane * ST32 + 16];
    u32* p2 = (u32*)&lVmT[lane * ST32 + 16];
    u32* p3 = (u32*)&lTWt[lane * ST32 + 16];
    u32* p4 = (u32*)&lTAt[lane * ST32 + 16];
#pragma unroll
    for (int q = 0; q < 8; q++) { p0[q] = 0; p1[q] = 0; p2[q] = 0; p3[q] = 0; p4[q] = 0; }
    if (lane < 16) {
      u32* q0 = (u32*)&lP[lane * ST32 + 16];
      u32* q1 = (u32*)&lQ[lane * ST32 + 16];
      u32* q2 = (u32*)&lBm[lane * ST32 + 16];
#pragma unroll
      for (int q = 0; q < 8; q++) { q0[q] = 0; q1[q] = 0; q2[q] = 0; }
    }
  }

  const long rowbase = (long)b * Tc + (long)(sp0 + col) * 16;
  const long gbase = rowbase * 2048 + (long)h * 64 + lane;
  float cw = 0.f;
#pragma unroll
  for (int i = 0; i < 16; i++) {
    long g = gbase + (long)i * 2048;
    float w = wS[g];
    float km = bf2f(kmS[g]), kk = bf2f(kkS[g]), bb = bf2f(bbS[g]);
    float vv = bf2f(vbS[g]), rr2 = bf2f(rbS[g]);
    float cwm = cw;
    cw += w;
    float E1 = __expf(cwm), E2 = __expf(-cw), E3 = __expf(cw);
    float xa = -kk * E1;
    lXa[i * ST64 + lane] = f2bf(xa);
    lX[i * STX + 64 + lane] = xa;
    lXr[i * ST64 + lane] = f2bf(rr2 * E3);
    float ya = bb * E2, yb = km * E2;
    lYa[i * ST64 + lane] = f2bf(ya);
    lYb[i * ST64 + lane] = f2bf(yb);
    lYaT[lane * ST32 + i] = f2bf(ya);
    lYbT[lane * ST32 + i] = f2bf(yb);
    lVmT[lane * ST32 + i] = f2bf(vv);
    if (i == 15) { lcl[lane] = E3; CLb[s * 64 + lane] = E3; }
  }
  __syncthreads();

  {
    f4_t aA = z4, aB = z4, aP = z4, aQ = z4;
#pragma unroll
    for (int kc = 0; kc < 2; kc++) {
      bf8_t xa = *(const bf8_t*)&lXa[l15 * ST64 + quad * 8 + 32 * kc];
      bf8_t xr = *(const bf8_t*)&lXr[l15 * ST64 + quad * 8 + 32 * kc];
      bf8_t ya = *(const bf8_t*)&lYa[l15 * ST64 + quad * 8 + 32 * kc];
      bf8_t yb = *(const bf8_t*)&lYb[l15 * ST64 + quad * 8 + 32 * kc];
      aA = MFMA16(xa, ya, aA);
      aB = MFMA16(xa, yb, aB);
      aP = MFMA16(xr, ya, aP);
      aQ = MFMA16(xr, yb, aQ);
    }
#pragma unroll
    for (int rg = 0; rg < 4; rg++) {
      int m = quad * 4 + rg;
      lA[m * 16 + l15] = (l15 < m) ? aA[rg] : 0.f;
      lBm[m * ST32 + l15] = (l15 < m) ? f2bf(aB[rg]) : (u16)0;
      lP[m * ST32 + l15] = (l15 <= m) ? f2bf(aP[rg]) : (u16)0;
      lQ[m * ST32 + l15] = (l15 <= m) ? f2bf(aQ[rg]) : (u16)0;
    }
  }
  __syncthreads();

#pragma unroll
  for (int nt = 0; nt < 4; nt++) {
    f4_t acc = z4;
    bf8_t a = *(const bf8_t*)&lBm[l15 * ST32 + quad * 8];
    bf8_t bb2 = *(const bf8_t*)&lVmT[(nt * 16 + l15) * ST32 + quad * 8];
    acc = MFMA16(a, bb2, acc);
#pragma unroll
    for (int rg = 0; rg < 4; rg++) lX[(quad * 4 + rg) * STX + nt * 16 + l15] = acc[rg];
  }
  __syncthreads();

  for (int i = 1; i < 16; i++) {
    float x0 = lX[i * STX + lane], x1 = lX[i * STX + 64 + lane];
    for (int j = 0; j < i; j++) {
      float aij = lA[i * 16 + j];
      x0 += aij * lX[j * STX + lane];
      x1 += aij * lX[j * STX + 64 + lane];
    }
    lX[i * STX + lane] = x0;
    lX[i * STX + 64 + lane] = x1;
  }
#pragma unroll
  for (int i = 0; i < 16; i++) {
    lTWt[lane * ST32 + i] = f2bf(lX[i * STX + lane]);
    lTAt[lane * ST32 + i] = f2bf(lX[i * STX + 64 + lane]);
  }
  __syncthreads();

#pragma unroll
  for (int nt = 0; nt < 4; nt++) {
    f4_t acc = z4;
    bf8_t p = *(const bf8_t*)&lP[l15 * ST32 + quad * 8];
    bf8_t q = *(const bf8_t*)&lQ[l15 * ST32 + quad * 8];
    bf8_t tw = *(const bf8_t*)&lTWt[(nt * 16 + l15) * ST32 + quad * 8];
    bf8_t vm = *(const bf8_t*)&lVmT[(nt * 16 + l15) * ST32 + quad * 8];
    acc = MFMA16(p, tw, acc);
    acc = MFMA16(q, vm, acc);
#pragma unroll
    for (int rg = 0; rg < 4; rg++)
      POWb[s * 1024 + (quad * 4 + rg) * 64 + nt * 16 + l15] = acc[rg];
  }
#pragma unroll
  for (int nt = 0; nt < 4; nt++) {
    f4_t acc = z4;
    bf8_t p = *(const bf8_t*)&lP[l15 * ST32 + quad * 8];
    bf8_t ta = *(const bf8_t*)&lTAt[(nt * 16 + l15) * ST32 + quad * 8];
    acc = MFMA16(p, ta, acc);
#pragma unroll
    for (int rg = 0; rg < 4; rg++) {
      float xr = bf2f(lXr[(quad * 4 + rg) * ST64 + nt * 16 + l15]);
      PAb[s * 1024 + (quad * 4 + rg) * 64 + nt * 16 + l15] = f2bf(acc[rg] + xr);
    }
  }

#pragma unroll
  for (int mt = 0; mt < 4; mt++)
#pragma unroll
    for (int nt = 0; nt < 4; nt++) {
      f4_t acc = z4;
      bf8_t tw = *(const bf8_t*)&lTWt[(mt * 16 + l15) * ST32 + quad * 8];
      bf8_t vm = *(const bf8_t*)&lVmT[(mt * 16 + l15) * ST32 + quad * 8];
      bf8_t yat = *(const bf8_t*)&lYaT[(nt * 16 + l15) * ST32 + quad * 8];
      bf8_t ybt = *(const bf8_t*)&lYbT[(nt * 16 + l15) * ST32 + quad * 8];
      acc = MFMA16(tw, yat, acc);
      acc = MFMA16(vm, ybt, acc);
      float cl = lcl[nt * 16 + l15];
#pragma unroll
      for (int rg = 0; rg < 4; rg++)
        Zb[s * 4096 + (mt * 16 + quad * 4 + rg) * 64 + nt * 16 + l15] = acc[rg] * cl;
    }
#pragma unroll
  for (int mt = 0; mt < 4; mt++)
#pragma unroll
    for (int nt = 0; nt < 4; nt++) {
      f4_t acc = z4;
      bf8_t yat = *(const bf8_t*)&lYaT[(mt * 16 + l15) * ST32 + quad * 8];
      bf8_t ta = *(const bf8_t*)&lTAt[(nt * 16 + l15) * ST32 + quad * 8];
      acc = MFMA16(yat, ta, acc);
#pragma unroll
      for (int rg = 0; rg < 4; rg++) {
        float cl = lcl[mt * 16 + quad * 4 + rg];
        GTb[s * 4096 + (mt * 16 + quad * 4 + rg) * 64 + nt * 16 + l15] = f2bf(acc[rg] * cl);
      }
    }
}

// phase B: sequential state propagation per (b,h). S_new = S*cl + Sbf*G + Z.
__global__ __launch_bounds__(256) void phaseB_kernel(
    const float* __restrict__ Zb, const u16* __restrict__ GTb, const float* __restrict__ CLb,
    u16* __restrict__ S0b, float* __restrict__ state, int CT, int init) {
  __shared__ u16 Sb[64 * ST64];
  const int bh = blockIdx.x;
  const int tid = threadIdx.x, wv = tid >> 6, lane = tid & 63;
  const int quad = lane >> 4, l15 = lane & 15;
  float S[4][4];
  if (init) {
#pragma unroll
    for (int nt = 0; nt < 4; nt++)
#pragma unroll
      for (int rg = 0; rg < 4; rg++) S[nt][rg] = 0.f;
  } else {
#pragma unroll
    for (int nt = 0; nt < 4; nt++)
#pragma unroll
      for (int rg = 0; rg < 4; rg++)
        S[nt][rg] = state[(long)bh * 4096 + (16 * wv + quad * 4 + rg) * 64 + nt * 16 + l15];
  }
  const f4_t z4 = {0.f, 0.f, 0.f, 0.f};
  for (int c = 0; c < CT; c++) {
    long s = (long)c * 64 + bh;
#pragma unroll
    for (int nt = 0; nt < 4; nt++)
#pragma unroll
      for (int rg = 0; rg < 4; rg++)
        Sb[(16 * wv + quad * 4 + rg) * ST64 + nt * 16 + l15] = f2bf(S[nt][rg]);
    __syncthreads();
    f4_t acc[4] = {z4, z4, z4, z4};
#pragma unroll
    for (int kc = 0; kc < 2; kc++) {
      bf8_t a = *(const bf8_t*)&Sb[(16 * wv + l15) * ST64 + quad * 8 + 32 * kc];
      *(uint4*)(S0b + s * 4096 + (16 * wv + l15) * 64 + quad * 8 + 32 * kc) = *(uint4*)&a;
#pragma unroll
      for (int nt = 0; nt < 4; nt++) {
        bf8_t g = *(const bf8_t*)(GTb + s * 4096 + (nt * 16 + l15) * 64 + quad * 8 + 32 * kc);
        acc[nt] = MFMA16(a, g, acc[nt]);
      }
    }
#pragma unroll
    for (int nt = 0; nt < 4; nt++) {
      float cl = CLb[s * 64 + nt * 16 + l15];
#pragma unroll
      for (int rg = 0; rg < 4; rg++) {
        float z = Zb[s * 4096 + (16 * wv + quad * 4 + rg) * 64 + nt * 16 + l15];
        S[nt][rg] = S[nt][rg] * cl + acc[nt][rg] + z;
      }
    }
    __syncthreads();
  }
#pragma unroll
  for (int nt = 0; nt < 4; nt++)
#pragma unroll
    for (int rg = 0; rg < 4; rg++)
      state[(long)bh * 4096 + (16 * wv + quad * 4 + rg) * 64 + nt * 16 + l15] = S[nt][rg];
}

// phase C: O = POW + PA * S0^T
__global__ __launch_bounds__(64) void phaseC_kernel(
    const float* __restrict__ POWb, const u16* __restrict__ PAb, const u16* __restrict__ S0b,
    float* __restrict__ O, int Tc, int sp0) {
  const int lane = threadIdx.x, quad = lane >> 4, l15 = lane & 15;
  const long tile = blockIdx.x;
  const int bh = (int)(tile & 63), col = (int)(tile >> 6);
  const int b = bh >> 5, h = bh & 31;
  const long s = tile;
  const f4_t z4 = {0.f, 0.f, 0.f, 0.f};
  f4_t acc[4] = {z4, z4, z4, z4};
#pragma unroll
  for (int kc = 0; kc < 2; kc++) {
    bf8_t a = *(const bf8_t*)(PAb + s * 1024 + l15 * 64 + quad * 8 + 32 * kc);
#pragma unroll
    for (int nt = 0; nt < 4; nt++) {
      bf8_t bo = *(const bf8_t*)(S0b + s * 4096 + (nt * 16 + l15) * 64 + quad * 8 + 32 * kc);
      acc[nt] = MFMA16(a, bo, acc[nt]);
    }
  }
  const long rowbase = (long)b * Tc + (long)(sp0 + col) * 16;
#pragma unroll
  for (int nt = 0; nt < 4; nt++)
#pragma unroll
    for (int rg = 0; rg < 4; rg++) {
      int i = quad * 4 + rg, v = nt * 16 + l15;
      float p = POWb[s * 1024 + i * 64 + v];
      O[(rowbase + i) * 2048 + (long)h * 64 + v] = p + acc[nt][rg];
    }
}

// ---------------- group-norm + residual + gate ----------------
__global__ __launch_bounds__(256) void epi_kernel(
    const float* __restrict__ o, const u16* __restrict__ r, const u16* __restrict__ k,
    const u16* __restrict__ v, const u16* __restrict__ g,
    const float* __restrict__ r_k, const float* __restrict__ gn_w, const float* __restrict__ gn_b,
    u16* __restrict__ y) {
  const int lane = threadIdx.x & 63;
  const long th = (((long)blockIdx.x * 256) + threadIdx.x) >> 6;
  const int hcol = (int)(th & 31) * 64 + lane;
  const long idx = th * 64 + lane;
  float ov = o[idx];
  float s = ov;
#pragma unroll
  for (int m = 32; m; m >>= 1) s += __shfl_xor(s, m, 64);
  float mu = s * (1.f / 64.f);
  float d = ov - mu;
  float vs = d * d;
#pragma unroll
  for (int m = 32; m; m >>= 1) vs += __shfl_xor(vs, m, 64);
  float on = d * rsqrtf(vs * (1.f / 64.f) + 6.4e-4f);
  on = on * gn_w[hcol] + gn_b[hcol];
  float rk = bf2f(r[idx]) * bf2f(k[idx]) * r_k[hcol];
#pragma unroll
  for (int m = 32; m; m >>= 1) rk += __shfl_xor(rk, m, 64);
  on += rk * bf2f(v[idx]);
  y[idx] = f2bf(on * bf2f(g[idx]));
}

// =============================== host ===============================
extern "C" void kernel_launch(void* const* d_in, const int* in_sizes, int n_in,
                              void* d_out, int out_size, void* d_ws, size_t ws_size,
                              hipStream_t stream) {
  constexpr int B = 2, T = 4096, H = 2048;
  const float* hst    = (const float*)d_in[0];
  const float* vfirst = (const float*)d_in[1];
  const float* x_r = (const float*)d_in[2];
  const float* x_w = (const float*)d_in[3];
  const float* x_k = (const float*)d_in[4];
  const float* x_v = (const float*)d_in[5];
  const float* x_a = (const float*)d_in[6];
  const float* x_g = (const float*)d_in[7];
  const float* k_k = (const float*)d_in[8];
  const float* k_a = (const float*)d_in[9];
  const float* r_k = (const float*)d_in[10];
  const float* w_r = (const float*)d_in[11];
  const float* w_k = (const float*)d_in[12];
  const float* w_v = (const float*)d_in[13];
  const float* w_o = (const float*)d_in[14];
  const float* wA  = (const float*)d_in[15];
  const float* wB  = (const float*)d_in[16];
  const float* wb  = (const float*)d_in[17];
  const float* aA  = (const float*)d_in[18];
  const float* aB  = (const float*)d_in[19];
  const float* ab  = (const float*)d_in[20];
  const float* vA  = (const float*)d_in[21];
  const float* vB  = (const float*)d_in[22];
  const float* vb  = (const float*)d_in[23];
  const float* gA  = (const float*)d_in[24];
  const float* gB  = (const float*)d_in[25];
  const float* gn_w= (const float*)d_in[26];
  const float* gn_b= (const float*)d_in[27];

  // weights kept: 4 HxH proj + wB/aB/vB (Hx128) + gB (Hx256) + Wf (768x4096)
  const size_t WEIGHT_BYTES = 4 * (size_t)H * H * 2 + 3 * (size_t)H * 128 * 2
                            + (size_t)H * 256 * 2 + (size_t)768 * 4096 * 2;
  const size_t STATE_BYTES = (size_t)64 * 4096 * 4;
  const size_t TILE_BYTES = 4096 + 2048 + 16384 + 8192 + 256 + 8192;  // POW PA Z GT CL S0

  int NC = -1, CT = 0;
  for (int pass = 0; pass < 2 && NC < 0; pass++) {
    for (int nc : {1, 2, 4, 8, 16}) {
      long Tc_ = T / nc;
      long R_ = (long)B * Tc_;
      long RH_ = R_ * H;
      // fp32 bufs (4) + bf16 bufs (7) + HD + s1all + weights + state + slack
      size_t base = (size_t)RH_ * 16 + (size_t)RH_ * 14 + (size_t)RH_ * 4 + (size_t)R_ * 1536
                  + WEIGHT_BYTES + STATE_BYTES + (4 << 20);
      int cols = (int)(Tc_ / 16);
      int found = 0;
      for (int ct : {64, 32, 16, 8}) {
        if (ct > cols) continue;
        if (pass == 0 && ct < 16) continue;
        size_t need = base + (size_t)64 * ct * TILE_BYTES;
        if (need <= ws_size) { NC = nc; CT = ct; found = 1; break; }
      }
      if (found) break;
    }
  }
  const int BS = 256;
  auto cdiv = [](long a, long b) { return (int)((a + b - 1) / b); };
  if (NC < 0) {
    fill_kernel<<<cdiv(out_size, BS), BS, 0, stream>>>(
        (float*)d_out, 200000.f + (float)(ws_size >> 20), out_size);
    return;
  }
  const int Tc = T / NC;
  const long R = (long)B * Tc;
  const long RH = R * H;
  const int cols = Tc / 16;
  const int NTILE = 64 * CT;

  char* ws = (char*)d_ws;
  size_t off = 0;
  auto alloc = [&](size_t bytes) -> void* {
    void* p = ws + off;
    off += (bytes + 255) & ~(size_t)255;
    return p;
  };
  float* F0 = (float*)alloc(RH * 4);
  float* F1 = (float*)alloc(RH * 4);
  float* F2 = (float*)alloc(RH * 4);
  float* F4 = (float*)alloc(RH * 4);
  u16* KM  = (u16*)alloc(RH * 2);
  u16* KK  = (u16*)alloc(RH * 2);
  u16* BBs = (u16*)alloc(RH * 2);
  u16* VBs = (u16*)alloc(RH * 2);
  u16* RBs = (u16*)alloc(RH * 2);
  u16* MIXB = (u16*)alloc(RH * 2);
  u16* G    = (u16*)alloc(RH * 2);
  u16* HD   = (u16*)alloc(RH * 4);          // [h | delta] bf16, R x 4096
  u16* s1all = (u16*)alloc(R * 1536);       // R x 768 bf16 (stage1 outputs)
  u16* wrb = (u16*)alloc((size_t)H * H * 2);
  u16* wkb = (u16*)alloc((size_t)H * H * 2);
  u16* wvb = (u16*)alloc((size_t)H * H * 2);
  u16* wob = (u16*)alloc((size_t)H * H * 2);
  u16* wBb = (u16*)alloc((size_t)H * 128 * 2);
  u16* aBb = (u16*)alloc((size_t)H * 128 * 2);
  u16* vBb = (u16*)alloc((size_t)H * 128 * 2);
  u16* gBb = (u16*)alloc((size_t)H * 256 * 2);
  u16* Wf  = (u16*)alloc((size_t)768 * 4096 * 2);
  float* state = (float*)alloc(STATE_BYTES);
  float* POWb = (float*)alloc((size_t)NTILE * 4096);
  u16*   PAb  = (u16*)alloc((size_t)NTILE * 2048);
  float* Zb   = (float*)alloc((size_t)NTILE * 16384);
  u16*   GTb  = (u16*)alloc((size_t)NTILE * 8192);
  float* CLb  = (float*)alloc((size_t)NTILE * 256);
  u16*   S0b  = (u16*)alloc((size_t)NTILE * 8192);
  float* Ob = F1;

  // big weights -> bf16 (once)
  padcvt_kernel<<<cdiv((long)H * H, BS), BS, 0, stream>>>(w_r, wrb, H, H, H, (long)H * H);
  padcvt_kernel<<<cdiv((long)H * H, BS), BS, 0, stream>>>(w_k, wkb, H, H, H, (long)H * H);
  padcvt_kernel<<<cdiv((long)H * H, BS), BS, 0, stream>>>(w_v, wvb, H, H, H, (long)H * H);
  padcvt_kernel<<<cdiv((long)H * H, BS), BS, 0, stream>>>(w_o, wob, H, H, H, (long)H * H);
  padcvt_kernel<<<cdiv((long)H * 128, BS), BS, 0, stream>>>(wB, wBb, H, 96, 128, (long)H * 128);
  padcvt_kernel<<<cdiv((long)H * 128, BS), BS, 0, stream>>>(aB, aBb, H, 96, 128, (long)H * 128);
  padcvt_kernel<<<cdiv((long)H * 128, BS), BS, 0, stream>>>(vB, vBb, H, 64, 128, (long)H * 128);
  padcvt_kernel<<<cdiv((long)H * 256, BS), BS, 0, stream>>>(gB, gBb, H, 256, 256, (long)H * 256);
  // fused stage1 weight stack: [wA|aA|vA|gA] x [1 | x-coef] (once)
  wf_kernel<<<cdiv((long)128 * 4096, BS), BS, 0, stream>>>(wA, x_w, Wf, 96, 0, (long)128 * 4096);
  wf_kernel<<<cdiv((long)128 * 4096, BS), BS, 0, stream>>>(aA, x_a, Wf, 96, 128, (long)128 * 4096);
  wf_kernel<<<cdiv((long)128 * 4096, BS), BS, 0, stream>>>(vA, x_v, Wf, 64, 256, (long)128 * 4096);
  wf_kernel<<<cdiv((long)384 * 4096, BS), BS, 0, stream>>>(gA, x_g, Wf, 256, 384, (long)384 * 4096);

  const long mixTot = (long)Tc * H / 4;
  const int mixG = cdiv(mixTot, BS);
  const int ehG = (int)(R * 32 / 4);

  for (int c = 0; c < NC; c++) {
    const int t0 = c * Tc;
    auto MIX = [&](const float* coef) {
      for (int b = 0; b < B; b++)
        mix1_kernel<<<mixG, BS, 0, stream>>>(hst + (long)b * T * H, coef,
                                             MIXB + (long)b * Tc * H, t0, Tc, mixTot);
    };
    dim3 gBig(16, (unsigned)(R / 128)), gF(6, (unsigned)(R / 128));
    dim3 g256((unsigned)(H / 256), (unsigned)(R / 256));

    // HD = [h | delta] (per chunk)
    for (int b = 0; b < B; b++)
      hd_kernel<<<mixG, BS, 0, stream>>>(hst + (long)b * T * H,
                                         HD + (long)b * Tc * 4096, t0, Tc, mixTot);
    // fused stage1: all four loras in one full-machine GEMM
    gemm_bt<5><<<gF, 256, 0, stream>>>(HD, Wf, s1all, (int)R, 768, 4096, 4096,
                                       nullptr, nullptr);
    // stage2: w -> F0 (w-logit), a -> F4
    gemm_bt<0><<<gBig, 256, 0, stream>>>(s1all, wBb, F0, (int)R, H, 128, 768,
                                         nullptr, nullptr);
    gemm_bt<0><<<gBig, 256, 0, stream>>>(s1all + 128, aBb, F4, (int)R, H, 128, 768,
                                         nullptr, nullptr);
    // v: raw proj + lerp
    MIX(x_v);
    gemm256_bt<0><<<g256, 512, 0, stream>>>(MIXB, wvb, F2, (int)R, H, H, (int)R, 0, 0);
    for (int b = 0; b < B; b++) {
      dim3 gHalf(16, (unsigned)(Tc / 128));
      gemm_bt<4><<<gHalf, 256, 0, stream>>>(s1all + (long)b * Tc * 768 + 256, vBb,
                                            F2 + (long)b * Tc * H, Tc, H, 128, 768,
                                            vfirst + ((long)b * T + t0) * H, vb);
    }
    // g stage2 -> G
    gemm_bt<1><<<gBig, 256, 0, stream>>>(s1all + 384, gBb, G, (int)R, H, 256, 768,
                                         nullptr, nullptr);
    // r -> RBs (bf16), k -> F1 (fp32)
    MIX(x_r);
    gemm256_bt<1><<<g256, 512, 0, stream>>>(MIXB, wrb, RBs, (int)R, H, H, (int)R, 0, 0);
    MIX(x_k);
    gemm256_bt<0><<<g256, 512, 0, stream>>>(MIXB, wkb, F1, (int)R, H, H, (int)R, 0, 0);
    // elementwise
    post1_kernel<<<ehG, 256, 0, stream>>>(F1, F4, F0, F2, KM, KK, BBs, VBs,
                                          k_k, k_a, wb, ab);
    // chunked scan
    for (int sp = 0; sp < cols; sp += CT) {
      phaseA_kernel<<<NTILE, 64, 0, stream>>>(F0, KM, KK, BBs, VBs, RBs,
                                              POWb, PAb, Zb, GTb, CLb, Tc, sp);
      phaseB_kernel<<<64, 256, 0, stream>>>(Zb, GTb, CLb, S0b, state, CT,
                                            (c == 0 && sp == 0) ? 1 : 0);
      phaseC_kernel<<<NTILE, 64, 0, stream>>>(POWb, PAb, S0b, Ob, Tc, sp);
    }
    // groupnorm + residual + gate -> MIXB
    epi_kernel<<<ehG, 256, 0, stream>>>(Ob, RBs, KM, VBs, G, r_k, gn_w, gn_b, MIXB);
    // output projection: single full-grid dispatch, row-remap folds the b-loop
    gemm256_bt<0><<<g256, 512, 0, stream>>>(MIXB, wob, (float*)d_out, (int)R, H, H,
                                            Tc, (long)t0, (long)T - Tc + t0);
  }
}

// Round 4
// 2851.958 us; speedup vs baseline: 1.3442x; 1.0823x over previous
//
#include <hip/hip_runtime.h>
#include <cstdint>
#include <cstddef>

typedef unsigned short u16;
typedef unsigned int u32;

typedef __bf16 bf8_t __attribute__((ext_vector_type(8)));
typedef float f4_t __attribute__((ext_vector_type(4)));

__device__ __forceinline__ u16 f2bf(float x) {
  u32 u = __float_as_uint(x);
  u = (u + 0x7fffu + ((u >> 16) & 1u)) >> 16;
  return (u16)u;
}
__device__ __forceinline__ float bf2f(u16 x) {
  u32 u = ((u32)x) << 16;
  return __uint_as_float(u);
}
__device__ __forceinline__ float sigf(float x) { return 1.f / (1.f + __expf(-x)); }

#define MFMA16(a, b, c) __builtin_amdgcn_mfma_f32_16x16x32_bf16(a, b, c, 0, 0, 0)

// ---------------- fill (sentinel) ----------------
__global__ void fill_kernel(float* p, float v, long n) {
  long i = (long)blockIdx.x * blockDim.x + threadIdx.x;
  if (i < n) p[i] = v;
}

// ---------------- fp32 -> bf16 weight convert with zero padding ----------------
__global__ void padcvt_kernel(const float* __restrict__ src, u16* __restrict__ dst,
                              int rows, int cols, int pc, long total) {
  long i = (long)blockIdx.x * blockDim.x + threadIdx.x;
  if (i >= total) return;
  int r = (int)(i / pc), c = (int)(i % pc);
  float v = (r < rows && c < cols) ? src[(long)r * cols + c] : 0.f;
  dst[i] = f2bf(v);
}

// ---------------- fused stage1 weight stack: Wf[row0+r][k] ----------------
// k<2048: W[r][k] ; k>=2048: W[r][k-2048]*coef[k-2048] ; r>=rows_valid: 0
__global__ void wf_kernel(const float* __restrict__ src, const float* __restrict__ coef,
                          u16* __restrict__ Wf, int rows_valid, int row0, long total) {
  long i = (long)blockIdx.x * blockDim.x + threadIdx.x;
  if (i >= total) return;
  int r = (int)(i >> 12);          // /4096
  int k = (int)(i & 4095);
  float v = 0.f;
  if (r < rows_valid) {
    int kk = k & 2047;
    v = src[(long)r * 2048 + kk];
    if (k >= 2048) v *= coef[kk];
  }
  Wf[(long)(row0 + r) * 4096 + k] = f2bf(v);
}

// ---------------- HD = [h | delta] bf16 (per chunk) ----------------
__global__ void hd_kernel(const float* __restrict__ h_b, u16* __restrict__ out_seg,
                          int t0, int Tc, long total4) {
  long i = (long)blockIdx.x * blockDim.x + threadIdx.x;
  if (i >= total4) return;
  long e = i * 4;
  const int H = 2048;
  int col = (int)(e % H);
  int tl = (int)(e / H);
  int tg = t0 + tl;
  const float* hp = h_b + (long)tg * H + col;
  float4 hv = *(const float4*)hp;
  float4 pv = make_float4(0.f, 0.f, 0.f, 0.f);
  if (tg > 0) pv = *(const float4*)(hp - H);
  u16* row = out_seg + (long)tl * 4096;
  uint2 ph, pd;
  ph.x = (u32)f2bf(hv.x) | ((u32)f2bf(hv.y) << 16);
  ph.y = (u32)f2bf(hv.z) | ((u32)f2bf(hv.w) << 16);
  pd.x = (u32)f2bf(pv.x - hv.x) | ((u32)f2bf(pv.y - hv.y) << 16);
  pd.y = (u32)f2bf(pv.z - hv.z) | ((u32)f2bf(pv.w - hv.w) << 16);
  *(uint2*)(row + col) = ph;
  *(uint2*)(row + 2048 + col) = pd;
}

// ---------------- token-shift mix ----------------
__global__ void mix1_kernel(const float* __restrict__ h_b, const float* __restrict__ coef,
                            u16* __restrict__ out_seg, int t0, int Tc, long total4) {
  long i = (long)blockIdx.x * blockDim.x + threadIdx.x;
  if (i >= total4) return;
  long e = i * 4;
  const int H = 2048;
  int col = (int)(e % H);
  int tl = (int)(e / H);
  int tg = t0 + tl;
  const float* hp = h_b + (long)tg * H + col;
  float4 hv = *(const float4*)hp;
  float4 pv = make_float4(0.f, 0.f, 0.f, 0.f);
  if (tg > 0) pv = *(const float4*)(hp - H);
  float4 cc = *(const float4*)(coef + col);
  uint2 pk;
  pk.x = (u32)f2bf(hv.x + (pv.x - hv.x) * cc.x) | ((u32)f2bf(hv.y + (pv.y - hv.y) * cc.y) << 16);
  pk.y = (u32)f2bf(hv.z + (pv.z - hv.z) * cc.z) | ((u32)f2bf(hv.w + (pv.w - hv.w) * cc.w) << 16);
  *(uint2*)(out_seg + e) = pk;
}

// ---------------- bf16 MFMA GEMM (128x128, reg-prefetch double-buffer) ----------------
// MODE 0: fp32. 1: bf16. 2: tanh->bf16. 3: sigmoid->bf16.
// MODE 5: fused stage1 (col<128 tanh, col<384 plain, else sigmoid) -> bf16.
// MODE 6: sigmoid(x + aux1[n]) -> bf16 (v-lora gate).
#define LDSW 40
template <int MODE>
__global__ __launch_bounds__(256) void gemm_bt(
    const u16* __restrict__ A, const u16* __restrict__ B, void* __restrict__ Cv,
    int M, int N, int K, int lda, const float* __restrict__ aux1) {
  __shared__ u16 sA[128 * LDSW];
  __shared__ u16 sB[128 * LDSW];
  const int tid = threadIdx.x;
  const long bm = (long)blockIdx.y * 128;
  const long bn = (long)blockIdx.x * 128;
  const int wave = tid >> 6, lane = tid & 63;
  const int wm = (wave >> 1) * 64, wn = (wave & 1) * 64;
  const int quad = lane >> 4, rr = lane & 15;

  f4_t acc[4][4];
  const f4_t zero = {0.f, 0.f, 0.f, 0.f};
#pragma unroll
  for (int i = 0; i < 4; i++)
#pragma unroll
    for (int j = 0; j < 4; j++) acc[i][j] = zero;

  const int c0 = tid, c1 = tid + 256;
  const u16* pa0 = A + (bm + (c0 >> 2)) * (long)lda + (c0 & 3) * 8;
  const u16* pa1 = A + (bm + (c1 >> 2)) * (long)lda + (c1 & 3) * 8;
  const u16* pb0 = B + (bn + (c0 >> 2)) * (long)K + (c0 & 3) * 8;
  const u16* pb1 = B + (bn + (c1 >> 2)) * (long)K + (c1 & 3) * 8;

  uint4 ra0, ra1, rb0, rb1;
#define LDG(k0)                              \
  {                                          \
    ra0 = *(const uint4*)(pa0 + (k0));       \
    ra1 = *(const uint4*)(pa1 + (k0));       \
    rb0 = *(const uint4*)(pb0 + (k0));       \
    rb1 = *(const uint4*)(pb1 + (k0));       \
  }
  LDG(0);
  for (int k0 = 0; k0 < K; k0 += 32) {
    __syncthreads();
    *(uint4*)(&sA[(c0 >> 2) * LDSW + (c0 & 3) * 8]) = ra0;
    *(uint4*)(&sA[(c1 >> 2) * LDSW + (c1 & 3) * 8]) = ra1;
    *(uint4*)(&sB[(c0 >> 2) * LDSW + (c0 & 3) * 8]) = rb0;
    *(uint4*)(&sB[(c1 >> 2) * LDSW + (c1 & 3) * 8]) = rb1;
    __syncthreads();
    if (k0 + 32 < K) LDG(k0 + 32);   // prefetch next K-step; latency hides under MFMA
    bf8_t af[4], bfv[4];
#pragma unroll
    for (int i = 0; i < 4; i++)
      af[i] = *(const bf8_t*)(&sA[(wm + i * 16 + rr) * LDSW + quad * 8]);
#pragma unroll
    for (int j = 0; j < 4; j++)
      bfv[j] = *(const bf8_t*)(&sB[(wn + j * 16 + rr) * LDSW + quad * 8]);
#pragma unroll
    for (int i = 0; i < 4; i++)
#pragma unroll
      for (int j = 0; j < 4; j++)
        acc[i][j] = MFMA16(af[i], bfv[j], acc[i][j]);
  }
#undef LDG
#pragma unroll
  for (int i = 0; i < 4; i++)
#pragma unroll
    for (int j = 0; j < 4; j++)
#pragma unroll
      for (int rg = 0; rg < 4; rg++) {
        long m = bm + wm + i * 16 + quad * 4 + rg;
        long n = bn + wn + j * 16 + rr;
        long id = m * (long)N + n;
        float x = acc[i][j][rg];
        if (MODE == 0) ((float*)Cv)[id] = x;
        else if (MODE == 1) ((u16*)Cv)[id] = f2bf(x);
        else if (MODE == 2) ((u16*)Cv)[id] = f2bf(tanhf(x));
        else if (MODE == 3) ((u16*)Cv)[id] = f2bf(sigf(x));
        else if (MODE == 5) {
          float y = (n < 128) ? tanhf(x) : ((n < 384) ? x : sigf(x));
          ((u16*)Cv)[id] = f2bf(y);
        } else if (MODE == 6) {
          ((u16*)Cv)[id] = f2bf(sigf(x + aux1[(int)n]));
        }
      }
}

// ================== 256x256 8-phase pipelined GEMM (T2+T3+T4+T5) ==================
// C[M,N] = A[M,K] * B[N,K]^T. bf16 in, MODE 0 fp32 out / MODE 1 bf16 out.
// Used only for K>=2048 (deep pipeline amortizes prologue/drain).
__device__ __forceinline__ void gload16(const u16* g, u16* l) {
  __builtin_amdgcn_global_load_lds((const __attribute__((address_space(1))) u32*)g,
                                   (__attribute__((address_space(3))) u32*)l, 16, 0, 0);
}

template <int MODE>
__global__ __launch_bounds__(512, 2) void gemm256_bt(
    const u16* __restrict__ A, const u16* __restrict__ Bw, void* __restrict__ Cv,
    int M, int N, int K, int rsp, long r0off, long r1off) {
  __shared__ u16 L[2][2][2][8192];
  const int tid = threadIdx.x;
  const int lane = tid & 63, w = tid >> 6;
  const int quad = lane >> 4, l15 = lane & 15;
  const long bm = (long)blockIdx.y * 256, bn = (long)blockIdx.x * 256;
  const int wm = (w >> 2) * 128, wn = (w & 3) * 64;
  const int NT = K >> 6;

  const int u0 = tid, u1 = tid + 512;
  const int ar0 = u0 >> 2, ar1 = u1 >> 2;
  const int aq0 = (u0 & 3) ^ (ar0 & 3), aq1 = (u1 & 3) ^ (ar1 & 3);
  const u16* gA0 = A + (bm + ar0) * (long)K + aq0 * 8;
  const u16* gA1 = A + (bm + ar1) * (long)K + aq1 * 8;
  const u16* gB0 = Bw + (bn + ar0) * (long)K + aq0 * 8;
  const u16* gB1 = Bw + (bn + ar1) * (long)K + aq1 * 8;

  const int qx = (quad ^ (l15 & 3)) * 8;
  const int roA = (wm + l15) * 32 + qx;
  const int roB = (wn + l15) * 32 + qx;

  f4_t acc[8][4];
#pragma unroll
  for (int i = 0; i < 8; i++)
#pragma unroll
    for (int j = 0; j < 4; j++) acc[i][j] = (f4_t){0.f, 0.f, 0.f, 0.f};

#define STG_A(buf, s, tt)                                   \
  {                                                         \
    long ko = ((long)(tt) << 6) + ((s) << 5);               \
    gload16(gA0 + ko, &L[buf][0][s][u0 * 8]);               \
    gload16(gA1 + ko, &L[buf][0][s][u1 * 8]);               \
  }
#define STG_B(buf, s, tt)                                   \
  {                                                         \
    long ko = ((long)(tt) << 6) + ((s) << 5);               \
    gload16(gB0 + ko, &L[buf][1][s][u0 * 8]);               \
    gload16(gB1 + ko, &L[buf][1][s][u1 * 8]);               \
  }
#define LDA4(P, o)                                          \
  _Pragma("unroll") for (int i = 0; i < 4; i++)             \
      aF[i] = *(const bf8_t*)((P) + roA + ((o) + i) * 512);
#define LDB4(P)                                             \
  _Pragma("unroll") for (int j = 0; j < 4; j++)             \
      bF[j] = *(const bf8_t*)((P) + roB + j * 512);
#define MFMA_BLK(base)                                      \
  __builtin_amdgcn_s_setprio(1);                            \
  _Pragma("unroll") for (int i = 0; i < 4; i++)             \
      _Pragma("unroll") for (int j = 0; j < 4; j++)         \
          acc[(base) + i][j] = MFMA16(aF[i], bF[j], acc[(base) + i][j]); \
  __builtin_amdgcn_s_setprio(0);
#define SBAR __builtin_amdgcn_s_barrier()

  STG_A(0, 0, 0); STG_B(0, 0, 0);
  STG_A(0, 1, 0); STG_B(0, 1, 0);
  if (NT > 1) { STG_A(1, 0, 1); STG_B(1, 0, 1); }
  asm volatile("s_waitcnt vmcnt(8)" ::: "memory");
  SBAR;

  bf8_t aF[4], bF[4];
  for (int t = 0; t < NT; ++t) {
    const int buf = t & 1;
    const u16* A0 = &L[buf][0][0][0];
    const u16* B0 = &L[buf][1][0][0];
    const u16* A1 = &L[buf][0][1][0];
    const u16* B1 = &L[buf][1][1][0];
    // ---- phase 1 ----
    LDA4(A0, 0);
    LDB4(B0);
    if (t + 1 < NT) STG_A(buf ^ 1, 1, t + 1);
    SBAR;
    asm volatile("s_waitcnt lgkmcnt(0)" ::: "memory");
    MFMA_BLK(0);
    SBAR;
    // ---- phase 2 ----
    LDA4(A0, 4);
    if (t + 1 < NT) STG_B(buf ^ 1, 1, t + 1);
    SBAR;
    asm volatile("s_waitcnt lgkmcnt(0)" ::: "memory");
    MFMA_BLK(4);
    if (t == NT - 1) asm volatile("s_waitcnt vmcnt(0)" ::: "memory");
    else asm volatile("s_waitcnt vmcnt(8)" ::: "memory");
    SBAR;
    // ---- phase 3 ----
    LDA4(A1, 0);
    LDB4(B1);
    if (t + 2 < NT) STG_A(buf, 0, t + 2);
    SBAR;
    asm volatile("s_waitcnt lgkmcnt(0)" ::: "memory");
    MFMA_BLK(0);
    SBAR;
    // ---- phase 4 ----
    LDA4(A1, 4);
    if (t + 2 < NT) STG_B(buf, 0, t + 2);
    SBAR;
    asm volatile("s_waitcnt lgkmcnt(0)" ::: "memory");
    MFMA_BLK(4);
    if (t == NT - 2) asm volatile("s_waitcnt vmcnt(4)" ::: "memory");
    else if (t < NT - 2) asm volatile("s_waitcnt vmcnt(8)" ::: "memory");
    SBAR;
  }

#pragma unroll
  for (int i = 0; i < 8; i++) {
#pragma unroll
    for (int rg = 0; rg < 4; rg++) {
      long mm = bm + wm + i * 16 + quad * 4 + rg;
      long crow = (mm < rsp) ? (mm + r0off) : (mm + r1off);
#pragma unroll
      for (int j = 0; j < 4; j++) {
        long n = bn + wn + j * 16 + l15;
        float x = acc[i][j][rg];
        if (MODE == 0) ((float*)Cv)[crow * (long)N + n] = x;
        else ((u16*)Cv)[crow * (long)N + n] = f2bf(x);
      }
    }
  }
#undef STG_A
#undef STG_B
#undef LDA4
#undef LDB4
#undef MFMA_BLK
#undef SBAR
}

// ---------------- post-GEMM elementwise (now also fuses the v_first lerp) ----------------
__global__ __launch_bounds__(256) void post1_kernel(
    const float* __restrict__ F1, const float* __restrict__ F4, float* F0,
    const float* __restrict__ F2, const u16* __restrict__ VL,
    const float* __restrict__ vfirst,
    u16* __restrict__ KM, u16* __restrict__ KK, u16* __restrict__ BB, u16* __restrict__ VB,
    const float* __restrict__ k_k, const float* __restrict__ k_a,
    const float* __restrict__ wb, const float* __restrict__ ab, int t0, int Tc) {
  const int lane = threadIdx.x & 63;
  const long th = (((long)blockIdx.x * 256) + threadIdx.x) >> 6;
  const int hcol = (int)(th & 31) * 64 + lane;
  const long idx = th * 64 + lane;
  const long r = th >> 5;
  float kraw = F1[idx];
  float kk0 = kraw * k_k[hcol];
  float ss = kk0 * kk0;
#pragma unroll
  for (int m = 32; m; m >>= 1) ss += __shfl_xor(ss, m, 64);
  float kkn = kk0 / fmaxf(sqrtf(ss), 1e-12f);
  float av = sigf(F4[idx] + ab[hcol]);
  float w = -0.6065306597126334f * sigf(F0[idx] + wb[hcol]);
  F0[idx] = w;
  KM[idx] = f2bf(kraw * (1.f + (av - 1.f) * k_a[hcol]));
  KK[idx] = f2bf(kkn);
  BB[idx] = f2bf(kkn * av);
  // v_first lerp: v = v_raw + (vfirst - v_raw) * VL
  float vraw = F2[idx];
  float sg = bf2f(VL[idx]);
  long vfi = ((r / Tc) * 4096 + t0 + (r % Tc)) * 2048 + hcol;
  VB[idx] = f2bf(vraw + (vfirst[vfi] - vraw) * sg);
}

// ================= chunked RWKV7 scan (L=16) =================
constexpr int ST64 = 72;   // u16 stride for [16][64]
constexpr int ST32 = 40;   // u16 stride for [.][32]
constexpr int STX = 132;   // fp32 stride for X [16][128]

__global__ __launch_bounds__(64) void phaseA_kernel(
    const float* __restrict__ wS, const u16* __restrict__ kmS, const u16* __restrict__ kkS,
    const u16* __restrict__ bbS, const u16* __restrict__ vbS, const u16* __restrict__ rbS,
    float* __restrict__ POWb, u16* __restrict__ PAb, float* __restrict__ Zb,
    u16* __restrict__ GTb, float* __restrict__ CLb, int Tc, int sp0) {
  __shared__ u16 lXa[16 * ST64], lXr[16 * ST64], lYa[16 * ST64], lYb[16 * ST64];
  __shared__ u16 lYaT[64 * ST32], lYbT[64 * ST32], lVmT[64 * ST32];
  __shared__ u16 lTWt[64 * ST32], lTAt[64 * ST32];
  __shared__ u16 lP[16 * ST32], lQ[16 * ST32], lBm[16 * ST32];
  __shared__ float lA[16 * 16];
  __shared__ float lX[16 * STX];
  __shared__ float lcl[64];
  const int lane = threadIdx.x;
  const int quad = lane >> 4, l15 = lane & 15;
  const long tile = blockIdx.x;
  const int bh = (int)(tile & 63);
  const int col = (int)(tile >> 6);
  const int b = bh >> 5, h = bh & 31;
  const long s = tile;
  const f4_t z4 = {0.f, 0.f, 0.f, 0.f};

  {
    u32* p0 = (u32*)&lYaT[lane * ST32 + 16];
    u32* p1 = (u32*)&lYbT[lane * ST32 + 16];
    u32* p2 = (u32*)&lVmT[lane * ST32 + 16];
    u32* p3 = (u32*)&lTWt[lane * ST32 + 16];
    u32* p4 = (u32*)&lTAt[lane * ST32 + 16];
#pragma unroll
    for (int q = 0; q < 8; q++) { p0[q] = 0; p1[q] = 0; p2[q] = 0; p3[q] = 0; p4[q] = 0; }
    if (lane < 16) {
      u32* q0 = (u32*)&lP[lane * ST32 + 16];
      u32* q1 = (u32*)&lQ[lane * ST32 + 16];
      u32* q2 = (u32*)&lBm[lane * ST32 + 16];
#pragma unroll
      for (int q = 0; q < 8; q++) { q0[q] = 0; q1[q] = 0; q2[q] = 0; }
    }
  }

  const long rowbase = (long)b * Tc + (long)(sp0 + col) * 16;
  const long gbase = rowbase * 2048 + (long)h * 64 + lane;
  float cw = 0.f;
#pragma unroll
  for (int i = 0; i < 16; i++) {
    long g = gbase + (long)i * 2048;
    float w = wS[g];
    float km = bf2f(kmS[g]), kk = bf2f(kkS[g]), bb = bf2f(bbS[g]);
    float vv = bf2f(vbS[g]), rr2 = bf2f(rbS[g]);
    float cwm = cw;
    cw += w;
    float E1 = __expf(cwm), E2 = __expf(-cw), E3 = __expf(cw);
    float xa = -kk * E1;
    lXa[i * ST64 + lane] = f2bf(xa);
    lX[i * STX + 64 + lane] = xa;
    lXr[i * ST64 + lane] = f2bf(rr2 * E3);
    float ya = bb * E2, yb = km * E2;
    lYa[i * ST64 + lane] = f2bf(ya);
    lYb[i * ST64 + lane] = f2bf(yb);
    lYaT[lane * ST32 + i] = f2bf(ya);
    lYbT[lane * ST32 + i] = f2bf(yb);
    lVmT[lane * ST32 + i] = f2bf(vv);
    if (i == 15) { lcl[lane] = E3; CLb[s * 64 + lane] = E3; }
  }
  __syncthreads();

  {
    f4_t aA = z4, aB = z4, aP = z4, aQ = z4;
#pragma unroll
    for (int kc = 0; kc < 2; kc++) {
      bf8_t xa = *(const bf8_t*)&lXa[l15 * ST64 + quad * 8 + 32 * kc];
      bf8_t xr = *(const bf8_t*)&lXr[l15 * ST64 + quad * 8 + 32 * kc];
      bf8_t ya = *(const bf8_t*)&lYa[l15 * ST64 + quad * 8 + 32 * kc];
      bf8_t yb = *(const bf8_t*)&lYb[l15 * ST64 + quad * 8 + 32 * kc];
      aA = MFMA16(xa, ya, aA);
      aB = MFMA16(xa, yb, aB);
      aP = MFMA16(xr, ya, aP);
      aQ = MFMA16(xr, yb, aQ);
    }
#pragma unroll
    for (int rg = 0; rg < 4; rg++) {
      int m = quad * 4 + rg;
      lA[m * 16 + l15] = (l15 < m) ? aA[rg] : 0.f;
      lBm[m * ST32 + l15] = (l15 < m) ? f2bf(aB[rg]) : (u16)0;
      lP[m * ST32 + l15] = (l15 <= m) ? f2bf(aP[rg]) : (u16)0;
      lQ[m * ST32 + l15] = (l15 <= m) ? f2bf(aQ[rg]) : (u16)0;
    }
  }
  __syncthreads();

#pragma unroll
  for (int nt = 0; nt < 4; nt++) {
    f4_t acc = z4;
    bf8_t a = *(const bf8_t*)&lBm[l15 * ST32 + quad * 8];
    bf8_t bb2 = *(const bf8_t*)&lVmT[(nt * 16 + l15) * ST32 + quad * 8];
    acc = MFMA16(a, bb2, acc);
#pragma unroll
    for (int rg = 0; rg < 4; rg++) lX[(quad * 4 + rg) * STX + nt * 16 + l15] = acc[rg];
  }
  __syncthreads();

  for (int i = 1; i < 16; i++) {
    float x0 = lX[i * STX + lane], x1 = lX[i * STX + 64 + lane];
    for (int j = 0; j < i; j++) {
      float aij = lA[i * 16 + j];
      x0 += aij * lX[j * STX + lane];
      x1 += aij * lX[j * STX + 64 + lane];
    }
    lX[i * STX + lane] = x0;
    lX[i * STX + 64 + lane] = x1;
  }
#pragma unroll
  for (int i = 0; i < 16; i++) {
    lTWt[lane * ST32 + i] = f2bf(lX[i * STX + lane]);
    lTAt[lane * ST32 + i] = f2bf(lX[i * STX + 64 + lane]);
  }
  __syncthreads();

#pragma unroll
  for (int nt = 0; nt < 4; nt++) {
    f4_t acc = z4;
    bf8_t p = *(const bf8_t*)&lP[l15 * ST32 + quad * 8];
    bf8_t q = *(const bf8_t*)&lQ[l15 * ST32 + quad * 8];
    bf8_t tw = *(const bf8_t*)&lTWt[(nt * 16 + l15) * ST32 + quad * 8];
    bf8_t vm = *(const bf8_t*)&lVmT[(nt * 16 + l15) * ST32 + quad * 8];
    acc = MFMA16(p, tw, acc);
    acc = MFMA16(q, vm, acc);
#pragma unroll
    for (int rg = 0; rg < 4; rg++)
      POWb[s * 1024 + (quad * 4 + rg) * 64 + nt * 16 + l15] = acc[rg];
  }
#pragma unroll
  for (int nt = 0; nt < 4; nt++) {
    f4_t acc = z4;
    bf8_t p = *(const bf8_t*)&lP[l15 * ST32 + quad * 8];
    bf8_t ta = *(const bf8_t*)&lTAt[(nt * 16 + l15) * ST32 + quad * 8];
    acc = MFMA16(p, ta, acc);
#pragma unroll
    for (int rg = 0; rg < 4; rg++) {
      float xr = bf2f(lXr[(quad * 4 + rg) * ST64 + nt * 16 + l15]);
      PAb[s * 1024 + (quad * 4 + rg) * 64 + nt * 16 + l15] = f2bf(acc[rg] + xr);
    }
  }

#pragma unroll
  for (int mt = 0; mt < 4; mt++)
#pragma unroll
    for (int nt = 0; nt < 4; nt++) {
      f4_t acc = z4;
      bf8_t tw = *(const bf8_t*)&lTWt[(mt * 16 + l15) * ST32 + quad * 8];
      bf8_t vm = *(const bf8_t*)&lVmT[(mt * 16 + l15) * ST32 + quad * 8];
      bf8_t yat = *(const bf8_t*)&lYaT[(nt * 16 + l15) * ST32 + quad * 8];
      bf8_t ybt = *(const bf8_t*)&lYbT[(nt * 16 + l15) * ST32 + quad * 8];
      acc = MFMA16(tw, yat, acc);
      acc = MFMA16(vm, ybt, acc);
      float cl = lcl[nt * 16 + l15];
#pragma unroll
      for (int rg = 0; rg < 4; rg++)
        Zb[s * 4096 + (mt * 16 + quad * 4 + rg) * 64 + nt * 16 + l15] = acc[rg] * cl;
    }
#pragma unroll
  for (int mt = 0; mt < 4; mt++)
#pragma unroll
    for (int nt = 0; nt < 4; nt++) {
      f4_t acc = z4;
      bf8_t yat = *(const bf8_t*)&lYaT[(mt * 16 + l15) * ST32 + quad * 8];
      bf8_t ta = *(const bf8_t*)&lTAt[(nt * 16 + l15) * ST32 + quad * 8];
      acc = MFMA16(yat, ta, acc);
#pragma unroll
      for (int rg = 0; rg < 4; rg++) {
        float cl = lcl[mt * 16 + quad * 4 + rg];
        GTb[s * 4096 + (mt * 16 + quad * 4 + rg) * 64 + nt * 16 + l15] = f2bf(acc[rg] * cl);
      }
    }
}

// phase B: sequential state propagation per (b,h). S_new = S*cl + Sbf*G + Z.
__global__ __launch_bounds__(256) void phaseB_kernel(
    const float* __restrict__ Zb, const u16* __restrict__ GTb, const float* __restrict__ CLb,
    u16* __restrict__ S0b, float* __restrict__ state, int CT, int init) {
  __shared__ u16 Sb[64 * ST64];
  const int bh = blockIdx.x;
  const int tid = threadIdx.x, wv = tid >> 6, lane = tid & 63;
  const int quad = lane >> 4, l15 = lane & 15;
  float S[4][4];
  if (init) {
#pragma unroll
    for (int nt = 0; nt < 4; nt++)
#pragma unroll
      for (int rg = 0; rg < 4; rg++) S[nt][rg] = 0.f;
  } else {
#pragma unroll
    for (int nt = 0; nt < 4; nt++)
#pragma unroll
      for (int rg = 0; rg < 4; rg++)
        S[nt][rg] = state[(long)bh * 4096 + (16 * wv + quad * 4 + rg) * 64 + nt * 16 + l15];
  }
  const f4_t z4 = {0.f, 0.f, 0.f, 0.f};
  for (int c = 0; c < CT; c++) {
    long s = (long)c * 64 + bh;
#pragma unroll
    for (int nt = 0; nt < 4; nt++)
#pragma unroll
      for (int rg = 0; rg < 4; rg++)
        Sb[(16 * wv + quad * 4 + rg) * ST64 + nt * 16 + l15] = f2bf(S[nt][rg]);
    __syncthreads();
    f4_t acc[4] = {z4, z4, z4, z4};
#pragma unroll
    for (int kc = 0; kc < 2; kc++) {
      bf8_t a = *(const bf8_t*)&Sb[(16 * wv + l15) * ST64 + quad * 8 + 32 * kc];
      *(uint4*)(S0b + s * 4096 + (16 * wv + l15) * 64 + quad * 8 + 32 * kc) = *(uint4*)&a;
#pragma unroll
      for (int nt = 0; nt < 4; nt++) {
        bf8_t g = *(const bf8_t*)(GTb + s * 4096 + (nt * 16 + l15) * 64 + quad * 8 + 32 * kc);
        acc[nt] = MFMA16(a, g, acc[nt]);
      }
    }
#pragma unroll
    for (int nt = 0; nt < 4; nt++) {
      float cl = CLb[s * 64 + nt * 16 + l15];
#pragma unroll
      for (int rg = 0; rg < 4; rg++) {
        float z = Zb[s * 4096 + (16 * wv + quad * 4 + rg) * 64 + nt * 16 + l15];
        S[nt][rg] = S[nt][rg] * cl + acc[nt][rg] + z;
      }
    }
    __syncthreads();
  }
#pragma unroll
  for (int nt = 0; nt < 4; nt++)
#pragma unroll
    for (int rg = 0; rg < 4; rg++)
      state[(long)bh * 4096 + (16 * wv + quad * 4 + rg) * 64 + nt * 16 + l15] = S[nt][rg];
}

// phase C: O = POW + PA * S0^T
__global__ __launch_bounds__(64) void phaseC_kernel(
    const float* __restrict__ POWb, const u16* __restrict__ PAb, const u16* __restrict__ S0b,
    float* __restrict__ O, int Tc, int sp0) {
  const int lane = threadIdx.x, quad = lane >> 4, l15 = lane & 15;
  const long tile = blockIdx.x;
  const int bh = (int)(tile & 63), col = (int)(tile >> 6);
  const int b = bh >> 5, h = bh & 31;
  const long s = tile;
  const f4_t z4 = {0.f, 0.f, 0.f, 0.f};
  f4_t acc[4] = {z4, z4, z4, z4};
#pragma unroll
  for (int kc = 0; kc < 2; kc++) {
    bf8_t a = *(const bf8_t*)(PAb + s * 1024 + l15 * 64 + quad * 8 + 32 * kc);
#pragma unroll
    for (int nt = 0; nt < 4; nt++) {
      bf8_t bo = *(const bf8_t*)(S0b + s * 4096 + (nt * 16 + l15) * 64 + quad * 8 + 32 * kc);
      acc[nt] = MFMA16(a, bo, acc[nt]);
    }
  }
  const long rowbase = (long)b * Tc + (long)(sp0 + col) * 16;
#pragma unroll
  for (int nt = 0; nt < 4; nt++)
#pragma unroll
    for (int rg = 0; rg < 4; rg++) {
      int i = quad * 4 + rg, v = nt * 16 + l15;
      float p = POWb[s * 1024 + i * 64 + v];
      O[(rowbase + i) * 2048 + (long)h * 64 + v] = p + acc[nt][rg];
    }
}

// ---------------- group-norm + residual + gate ----------------
__global__ __launch_bounds__(256) void epi_kernel(
    const float* __restrict__ o, const u16* __restrict__ r, const u16* __restrict__ k,
    const u16* __restrict__ v, const u16* __restrict__ g,
    const float* __restrict__ r_k, const float* __restrict__ gn_w, const float* __restrict__ gn_b,
    u16* __restrict__ y) {
  const int lane = threadIdx.x & 63;
  const long th = (((long)blockIdx.x * 256) + threadIdx.x) >> 6;
  const int hcol = (int)(th & 31) * 64 + lane;
  const long idx = th * 64 + lane;
  float ov = o[idx];
  float s = ov;
#pragma unroll
  for (int m = 32; m; m >>= 1) s += __shfl_xor(s, m, 64);
  float mu = s * (1.f / 64.f);
  float d = ov - mu;
  float vs = d * d;
#pragma unroll
  for (int m = 32; m; m >>= 1) vs += __shfl_xor(vs, m, 64);
  float on = d * rsqrtf(vs * (1.f / 64.f) + 6.4e-4f);
  on = on * gn_w[hcol] + gn_b[hcol];
  float rk = bf2f(r[idx]) * bf2f(k[idx]) * r_k[hcol];
#pragma unroll
  for (int m = 32; m; m >>= 1) rk += __shfl_xor(rk, m, 64);
  on += rk * bf2f(v[idx]);
  y[idx] = f2bf(on * bf2f(g[idx]));
}

// =============================== host ===============================
extern "C" void kernel_launch(void* const* d_in, const int* in_sizes, int n_in,
                              void* d_out, int out_size, void* d_ws, size_t ws_size,
                              hipStream_t stream) {
  constexpr int B = 2, T = 4096, H = 2048;
  const float* hst    = (const float*)d_in[0];
  const float* vfirst = (const float*)d_in[1];
  const float* x_r = (const float*)d_in[2];
  const float* x_w = (const float*)d_in[3];
  const float* x_k = (const float*)d_in[4];
  const float* x_v = (const float*)d_in[5];
  const float* x_a = (const float*)d_in[6];
  const float* x_g = (const float*)d_in[7];
  const float* k_k = (const float*)d_in[8];
  const float* k_a = (const float*)d_in[9];
  const float* r_k = (const float*)d_in[10];
  const float* w_r = (const float*)d_in[11];
  const float* w_k = (const float*)d_in[12];
  const float* w_v = (const float*)d_in[13];
  const float* w_o = (const float*)d_in[14];
  const float* wA  = (const float*)d_in[15];
  const float* wB  = (const float*)d_in[16];
  const float* wb  = (const float*)d_in[17];
  const float* aA  = (const float*)d_in[18];
  const float* aB  = (const float*)d_in[19];
  const float* ab  = (const float*)d_in[20];
  const float* vA  = (const float*)d_in[21];
  const float* vB  = (const float*)d_in[22];
  const float* vb  = (const float*)d_in[23];
  const float* gA  = (const float*)d_in[24];
  const float* gB  = (const float*)d_in[25];
  const float* gn_w= (const float*)d_in[26];
  const float* gn_b= (const float*)d_in[27];

  // weights kept: 4 HxH proj + wB/aB/vB (Hx128) + gB (Hx256) + Wf (768x4096)
  const size_t WEIGHT_BYTES = 4 * (size_t)H * H * 2 + 3 * (size_t)H * 128 * 2
                            + (size_t)H * 256 * 2 + (size_t)768 * 4096 * 2;
  const size_t STATE_BYTES = (size_t)64 * 4096 * 4;
  const size_t TILE_BYTES = 4096 + 2048 + 16384 + 8192 + 256 + 8192;  // POW PA Z GT CL S0

  int NC = -1, CT = 0;
  for (int pass = 0; pass < 2 && NC < 0; pass++) {
    for (int nc : {1, 2, 4, 8, 16}) {
      long Tc_ = T / nc;
      long R_ = (long)B * Tc_;
      long RH_ = R_ * H;
      // fp32 bufs (4) + bf16 bufs (8, incl VL) + HD + s1all + weights + state + slack
      size_t base = (size_t)RH_ * 16 + (size_t)RH_ * 16 + (size_t)RH_ * 4 + (size_t)R_ * 1536
                  + WEIGHT_BYTES + STATE_BYTES + (4 << 20);
      int cols = (int)(Tc_ / 16);
      int found = 0;
      for (int ct : {64, 32, 16, 8}) {
        if (ct > cols) continue;
        if (pass == 0 && ct < 16) continue;
        size_t need = base + (size_t)64 * ct * TILE_BYTES;
        if (need <= ws_size) { NC = nc; CT = ct; found = 1; break; }
      }
      if (found) break;
    }
  }
  const int BS = 256;
  auto cdiv = [](long a, long b) { return (int)((a + b - 1) / b); };
  if (NC < 0) {
    fill_kernel<<<cdiv(out_size, BS), BS, 0, stream>>>(
        (float*)d_out, 200000.f + (float)(ws_size >> 20), out_size);
    return;
  }
  const int Tc = T / NC;
  const long R = (long)B * Tc;
  const long RH = R * H;
  const int cols = Tc / 16;
  const int NTILE = 64 * CT;

  char* ws = (char*)d_ws;
  size_t off = 0;
  auto alloc = [&](size_t bytes) -> void* {
    void* p = ws + off;
    off += (bytes + 255) & ~(size_t)255;
    return p;
  };
  float* F0 = (float*)alloc(RH * 4);
  float* F1 = (float*)alloc(RH * 4);
  float* F2 = (float*)alloc(RH * 4);
  float* F4 = (float*)alloc(RH * 4);
  u16* KM  = (u16*)alloc(RH * 2);
  u16* KK  = (u16*)alloc(RH * 2);
  u16* BBs = (u16*)alloc(RH * 2);
  u16* VBs = (u16*)alloc(RH * 2);
  u16* RBs = (u16*)alloc(RH * 2);
  u16* MIXB = (u16*)alloc(RH * 2);
  u16* G    = (u16*)alloc(RH * 2);
  u16* VL   = (u16*)alloc(RH * 2);          // v-lora sigmoid gate (bf16)
  u16* HD   = (u16*)alloc(RH * 4);          // [h | delta] bf16, R x 4096
  u16* s1all = (u16*)alloc(R * 1536);       // R x 768 bf16 (stage1 outputs)
  u16* wrb = (u16*)alloc((size_t)H * H * 2);
  u16* wkb = (u16*)alloc((size_t)H * H * 2);
  u16* wvb = (u16*)alloc((size_t)H * H * 2);
  u16* wob = (u16*)alloc((size_t)H * H * 2);
  u16* wBb = (u16*)alloc((size_t)H * 128 * 2);
  u16* aBb = (u16*)alloc((size_t)H * 128 * 2);
  u16* vBb = (u16*)alloc((size_t)H * 128 * 2);
  u16* gBb = (u16*)alloc((size_t)H * 256 * 2);
  u16* Wf  = (u16*)alloc((size_t)768 * 4096 * 2);
  float* state = (float*)alloc(STATE_BYTES);
  float* POWb = (float*)alloc((size_t)NTILE * 4096);
  u16*   PAb  = (u16*)alloc((size_t)NTILE * 2048);
  float* Zb   = (float*)alloc((size_t)NTILE * 16384);
  u16*   GTb  = (u16*)alloc((size_t)NTILE * 8192);
  float* CLb  = (float*)alloc((size_t)NTILE * 256);
  u16*   S0b  = (u16*)alloc((size_t)NTILE * 8192);
  float* Ob = F1;

  // big weights -> bf16 (once)
  padcvt_kernel<<<cdiv((long)H * H, BS), BS, 0, stream>>>(w_r, wrb, H, H, H, (long)H * H);
  padcvt_kernel<<<cdiv((long)H * H, BS), BS, 0, stream>>>(w_k, wkb, H, H, H, (long)H * H);
  padcvt_kernel<<<cdiv((long)H * H, BS), BS, 0, stream>>>(w_v, wvb, H, H, H, (long)H * H);
  padcvt_kernel<<<cdiv((long)H * H, BS), BS, 0, stream>>>(w_o, wob, H, H, H, (long)H * H);
  padcvt_kernel<<<cdiv((long)H * 128, BS), BS, 0, stream>>>(wB, wBb, H, 96, 128, (long)H * 128);
  padcvt_kernel<<<cdiv((long)H * 128, BS), BS, 0, stream>>>(aB, aBb, H, 96, 128, (long)H * 128);
  padcvt_kernel<<<cdiv((long)H * 128, BS), BS, 0, stream>>>(vB, vBb, H, 64, 128, (long)H * 128);
  padcvt_kernel<<<cdiv((long)H * 256, BS), BS, 0, stream>>>(gB, gBb, H, 256, 256, (long)H * 256);
  // fused stage1 weight stack: [wA|aA|vA|gA] x [1 | x-coef] (once)
  wf_kernel<<<cdiv((long)128 * 4096, BS), BS, 0, stream>>>(wA, x_w, Wf, 96, 0, (long)128 * 4096);
  wf_kernel<<<cdiv((long)128 * 4096, BS), BS, 0, stream>>>(aA, x_a, Wf, 96, 128, (long)128 * 4096);
  wf_kernel<<<cdiv((long)128 * 4096, BS), BS, 0, stream>>>(vA, x_v, Wf, 64, 256, (long)128 * 4096);
  wf_kernel<<<cdiv((long)384 * 4096, BS), BS, 0, stream>>>(gA, x_g, Wf, 256, 384, (long)384 * 4096);

  const long mixTot = (long)Tc * H / 4;
  const int mixG = cdiv(mixTot, BS);
  const int ehG = (int)(R * 32 / 4);

  for (int c = 0; c < NC; c++) {
    const int t0 = c * Tc;
    auto MIX = [&](const float* coef) {
      for (int b = 0; b < B; b++)
        mix1_kernel<<<mixG, BS, 0, stream>>>(hst + (long)b * T * H, coef,
                                             MIXB + (long)b * Tc * H, t0, Tc, mixTot);
    };
    dim3 gBig(16, (unsigned)(R / 128)), gF(6, (unsigned)(R / 128));
    dim3 g256((unsigned)(H / 256), (unsigned)(R / 256));

    // HD = [h | delta] (per chunk)
    for (int b = 0; b < B; b++)
      hd_kernel<<<mixG, BS, 0, stream>>>(hst + (long)b * T * H,
                                         HD + (long)b * Tc * 4096, t0, Tc, mixTot);
    // fused stage1: all four loras in one full-machine GEMM
    gemm_bt<5><<<gF, 256, 0, stream>>>(HD, Wf, s1all, (int)R, 768, 4096, 4096, nullptr);
    // stage2: w -> F0 (w-logit), a -> F4
    gemm_bt<0><<<gBig, 256, 0, stream>>>(s1all, wBb, F0, (int)R, H, 128, 768, nullptr);
    gemm_bt<0><<<gBig, 256, 0, stream>>>(s1all + 128, aBb, F4, (int)R, H, 128, 768, nullptr);
    // v: raw proj (gemm256) + gate GEMM (lerp folded into post1)
    MIX(x_v);
    gemm256_bt<0><<<g256, 512, 0, stream>>>(MIXB, wvb, F2, (int)R, H, H, (int)R, 0, 0);
    gemm_bt<6><<<gBig, 256, 0, stream>>>(s1all + 256, vBb, VL, (int)R, H, 128, 768, vb);
    // g stage2 -> G
    gemm_bt<1><<<gBig, 256, 0, stream>>>(s1all + 384, gBb, G, (int)R, H, 256, 768, nullptr);
    // r -> RBs (bf16), k -> F1 (fp32)
    MIX(x_r);
    gemm256_bt<1><<<g256, 512, 0, stream>>>(MIXB, wrb, RBs, (int)R, H, H, (int)R, 0, 0);
    MIX(x_k);
    gemm256_bt<0><<<g256, 512, 0, stream>>>(MIXB, wkb, F1, (int)R, H, H, (int)R, 0, 0);
    // elementwise (incl. fused v_first lerp)
    post1_kernel<<<ehG, 256, 0, stream>>>(F1, F4, F0, F2, VL, vfirst,
                                          KM, KK, BBs, VBs, k_k, k_a, wb, ab, t0, Tc);
    // chunked scan
    for (int sp = 0; sp < cols; sp += CT) {
      phaseA_kernel<<<NTILE, 64, 0, stream>>>(F0, KM, KK, BBs, VBs, RBs,
                                              POWb, PAb, Zb, GTb, CLb, Tc, sp);
      phaseB_kernel<<<64, 256, 0, stream>>>(Zb, GTb, CLb, S0b, state, CT,
                                            (c == 0 && sp == 0) ? 1 : 0);
      phaseC_kernel<<<NTILE, 64, 0, stream>>>(POWb, PAb, S0b, Ob, Tc, sp);
    }
    // groupnorm + residual + gate -> MIXB
    epi_kernel<<<ehG, 256, 0, stream>>>(Ob, RBs, KM, VBs, G, r_k, gn_w, gn_b, MIXB);
    // output projection: single full-grid dispatch, row-remap folds the b-loop
    gemm256_bt<0><<<g256, 512, 0, stream>>>(MIXB, wob, (float*)d_out, (int)R, H, H,
                                            Tc, (long)t0, (long)T - Tc + t0);
  }
}

// Round 5
// 2744.643 us; speedup vs baseline: 1.3967x; 1.0391x over previous
//
#include <hip/hip_runtime.h>
#include <cstdint>
#include <cstddef>

typedef unsigned short u16;
typedef unsigned int u32;

typedef __bf16 bf8_t __attribute__((ext_vector_type(8)));
typedef float f4_t __attribute__((ext_vector_type(4)));

__device__ __forceinline__ u16 f2bf(float x) {
  u32 u = __float_as_uint(x);
  u = (u + 0x7fffu + ((u >> 16) & 1u)) >> 16;
  return (u16)u;
}
__device__ __forceinline__ float bf2f(u16 x) {
  u32 u = ((u32)x) << 16;
  return __uint_as_float(u);
}
__device__ __forceinline__ float sigf(float x) { return 1.f / (1.f + __expf(-x)); }

#define MFMA16(a, b, c) __builtin_amdgcn_mfma_f32_16x16x32_bf16(a, b, c, 0, 0, 0)

// ---------------- fill (sentinel) ----------------
__global__ void fill_kernel(float* p, float v, long n) {
  long i = (long)blockIdx.x * blockDim.x + threadIdx.x;
  if (i < n) p[i] = v;
}

// ---------------- fp32 -> bf16 weight convert with zero padding ----------------
__global__ void padcvt_kernel(const float* __restrict__ src, u16* __restrict__ dst,
                              int rows, int cols, int pc, long total) {
  long i = (long)blockIdx.x * blockDim.x + threadIdx.x;
  if (i >= total) return;
  int r = (int)(i / pc), c = (int)(i % pc);
  float v = (r < rows && c < cols) ? src[(long)r * cols + c] : 0.f;
  dst[i] = f2bf(v);
}

// ---------------- fused stage1 weight stack: Wf[row0+r][k] ----------------
__global__ void wf_kernel(const float* __restrict__ src, const float* __restrict__ coef,
                          u16* __restrict__ Wf, int rows_valid, int row0, long total) {
  long i = (long)blockIdx.x * blockDim.x + threadIdx.x;
  if (i >= total) return;
  int r = (int)(i >> 12);          // /4096
  int k = (int)(i & 4095);
  float v = 0.f;
  if (r < rows_valid) {
    int kk = k & 2047;
    v = src[(long)r * 2048 + kk];
    if (k >= 2048) v *= coef[kk];
  }
  Wf[(long)(row0 + r) * 4096 + k] = f2bf(v);
}

// ---------------- block-diag stacked stage2 weight: Wab[4096][256] ----------------
// rows 0..2047: [wB(96, zero-pad to 128) | 0(128)] ; rows 2048..4095: [0 | aB(96,pad)]
__global__ void wab_kernel(const float* __restrict__ wB, const float* __restrict__ aB,
                           u16* __restrict__ Wab, long total) {
  long i = (long)blockIdx.x * blockDim.x + threadIdx.x;
  if (i >= total) return;
  int r = (int)(i >> 8), k = (int)(i & 255);
  float v = 0.f;
  if (r < 2048) { if (k < 96) v = wB[(long)r * 96 + k]; }
  else { int rr = r - 2048; if (k >= 128 && k < 224) v = aB[(long)rr * 96 + (k - 128)]; }
  Wab[i] = f2bf(v);
}

// ---------------- HD = [h | delta] bf16 (per chunk) ----------------
__global__ void hd_kernel(const float* __restrict__ h_b, u16* __restrict__ out_seg,
                          int t0, int Tc, long total4) {
  long i = (long)blockIdx.x * blockDim.x + threadIdx.x;
  if (i >= total4) return;
  long e = i * 4;
  const int H = 2048;
  int col = (int)(e % H);
  int tl = (int)(e / H);
  int tg = t0 + tl;
  const float* hp = h_b + (long)tg * H + col;
  float4 hv = *(const float4*)hp;
  float4 pv = make_float4(0.f, 0.f, 0.f, 0.f);
  if (tg > 0) pv = *(const float4*)(hp - H);
  u16* row = out_seg + (long)tl * 4096;
  uint2 ph, pd;
  ph.x = (u32)f2bf(hv.x) | ((u32)f2bf(hv.y) << 16);
  ph.y = (u32)f2bf(hv.z) | ((u32)f2bf(hv.w) << 16);
  pd.x = (u32)f2bf(pv.x - hv.x) | ((u32)f2bf(pv.y - hv.y) << 16);
  pd.y = (u32)f2bf(pv.z - hv.z) | ((u32)f2bf(pv.w - hv.w) << 16);
  *(uint2*)(row + col) = ph;
  *(uint2*)(row + 2048 + col) = pd;
}

// ---------------- token-shift mix ----------------
__global__ void mix1_kernel(const float* __restrict__ h_b, const float* __restrict__ coef,
                            u16* __restrict__ out_seg, int t0, int Tc, long total4) {
  long i = (long)blockIdx.x * blockDim.x + threadIdx.x;
  if (i >= total4) return;
  long e = i * 4;
  const int H = 2048;
  int col = (int)(e % H);
  int tl = (int)(e / H);
  int tg = t0 + tl;
  const float* hp = h_b + (long)tg * H + col;
  float4 hv = *(const float4*)hp;
  float4 pv = make_float4(0.f, 0.f, 0.f, 0.f);
  if (tg > 0) pv = *(const float4*)(hp - H);
  float4 cc = *(const float4*)(coef + col);
  uint2 pk;
  pk.x = (u32)f2bf(hv.x + (pv.x - hv.x) * cc.x) | ((u32)f2bf(hv.y + (pv.y - hv.y) * cc.y) << 16);
  pk.y = (u32)f2bf(hv.z + (pv.z - hv.z) * cc.z) | ((u32)f2bf(hv.w + (pv.w - hv.w) * cc.w) << 16);
  *(uint2*)(out_seg + e) = pk;
}

// ---------------- bf16 MFMA GEMM (128x128, 2-deep LDG ping-pong prefetch) ----------------
// Requires K % 64 == 0. MODE 0: fp32. 1: bf16. 2: tanh. 3: sigmoid.
// MODE 5: fused stage1 (col<128 tanh, col<384 plain, else sigmoid) -> bf16.
// MODE 6: sigmoid(x + aux1[n]) -> bf16.
#define LDSW 40
template <int MODE>
__global__ __launch_bounds__(256) void gemm_bt(
    const u16* __restrict__ A, const u16* __restrict__ B, void* __restrict__ Cv,
    int M, int N, int K, int lda, const float* __restrict__ aux1) {
  __shared__ u16 sA[128 * LDSW];
  __shared__ u16 sB[128 * LDSW];
  const int tid = threadIdx.x;
  const long bm = (long)blockIdx.y * 128;
  const long bn = (long)blockIdx.x * 128;
  const int wave = tid >> 6, lane = tid & 63;
  const int wm = (wave >> 1) * 64, wn = (wave & 1) * 64;
  const int quad = lane >> 4, rr = lane & 15;

  f4_t acc[4][4];
  const f4_t zero = {0.f, 0.f, 0.f, 0.f};
#pragma unroll
  for (int i = 0; i < 4; i++)
#pragma unroll
    for (int j = 0; j < 4; j++) acc[i][j] = zero;

  const int c0 = tid, c1 = tid + 256;
  const u16* pa0 = A + (bm + (c0 >> 2)) * (long)lda + (c0 & 3) * 8;
  const u16* pa1 = A + (bm + (c1 >> 2)) * (long)lda + (c1 & 3) * 8;
  const u16* pb0 = B + (bn + (c0 >> 2)) * (long)K + (c0 & 3) * 8;
  const u16* pb1 = B + (bn + (c1 >> 2)) * (long)K + (c1 & 3) * 8;

  uint4 a0A, a1A, b0A, b1A, a0B, a1B, b0B, b1B;
#define LDGA(k0)                            \
  {                                         \
    a0A = *(const uint4*)(pa0 + (k0));      \
    a1A = *(const uint4*)(pa1 + (k0));      \
    b0A = *(const uint4*)(pb0 + (k0));      \
    b1A = *(const uint4*)(pb1 + (k0));      \
  }
#define LDGB(k0)                            \
  {                                         \
    a0B = *(const uint4*)(pa0 + (k0));      \
    a1B = *(const uint4*)(pa1 + (k0));      \
    b0B = *(const uint4*)(pb0 + (k0));      \
    b1B = *(const uint4*)(pb1 + (k0));      \
  }
#define STLDS(ra0, ra1, rb0, rb1)                          \
  {                                                        \
    *(uint4*)(&sA[(c0 >> 2) * LDSW + (c0 & 3) * 8]) = ra0; \
    *(uint4*)(&sA[(c1 >> 2) * LDSW + (c1 & 3) * 8]) = ra1; \
    *(uint4*)(&sB[(c0 >> 2) * LDSW + (c0 & 3) * 8]) = rb0; \
    *(uint4*)(&sB[(c1 >> 2) * LDSW + (c1 & 3) * 8]) = rb1; \
  }
#define COMPUTE                                                        \
  {                                                                    \
    bf8_t af[4], bfv[4];                                               \
    _Pragma("unroll") for (int i = 0; i < 4; i++)                      \
        af[i] = *(const bf8_t*)(&sA[(wm + i * 16 + rr) * LDSW + quad * 8]); \
    _Pragma("unroll") for (int j = 0; j < 4; j++)                      \
        bfv[j] = *(const bf8_t*)(&sB[(wn + j * 16 + rr) * LDSW + quad * 8]); \
    _Pragma("unroll") for (int i = 0; i < 4; i++)                      \
        _Pragma("unroll") for (int j = 0; j < 4; j++)                  \
            acc[i][j] = MFMA16(af[i], bfv[j], acc[i][j]);              \
  }

  LDGA(0);
  LDGB(32);
  for (int k0 = 0; k0 < K; k0 += 64) {
    __syncthreads();
    STLDS(a0A, a1A, b0A, b1A);
    __syncthreads();
    if (k0 + 64 < K) LDGA(k0 + 64);
    COMPUTE;
    __syncthreads();
    STLDS(a0B, a1B, b0B, b1B);
    __syncthreads();
    if (k0 + 96 < K) LDGB(k0 + 96);
    COMPUTE;
  }
#undef LDGA
#undef LDGB
#undef STLDS
#undef COMPUTE
#pragma unroll
  for (int i = 0; i < 4; i++)
#pragma unroll
    for (int j = 0; j < 4; j++)
#pragma unroll
      for (int rg = 0; rg < 4; rg++) {
        long m = bm + wm + i * 16 + quad * 4 + rg;
        long n = bn + wn + j * 16 + rr;
        long id = m * (long)N + n;
        float x = acc[i][j][rg];
        if (MODE == 0) ((float*)Cv)[id] = x;
        else if (MODE == 1) ((u16*)Cv)[id] = f2bf(x);
        else if (MODE == 2) ((u16*)Cv)[id] = f2bf(tanhf(x));
        else if (MODE == 3) ((u16*)Cv)[id] = f2bf(sigf(x));
        else if (MODE == 5) {
          float y = (n < 128) ? tanhf(x) : ((n < 384) ? x : sigf(x));
          ((u16*)Cv)[id] = f2bf(y);
        } else if (MODE == 6) {
          ((u16*)Cv)[id] = f2bf(sigf(x + aux1[(int)n]));
        }
      }
}

// ================== 256x256 8-phase pipelined GEMM (T2+T3+T4+T5) ==================
__device__ __forceinline__ void gload16(const u16* g, u16* l) {
  __builtin_amdgcn_global_load_lds((const __attribute__((address_space(1))) u32*)g,
                                   (__attribute__((address_space(3))) u32*)l, 16, 0, 0);
}

template <int MODE>
__global__ __launch_bounds__(512, 2) void gemm256_bt(
    const u16* __restrict__ A, const u16* __restrict__ Bw, void* __restrict__ Cv,
    int M, int N, int K, int rsp, long r0off, long r1off) {
  __shared__ u16 L[2][2][2][8192];
  const int tid = threadIdx.x;
  const int lane = tid & 63, w = tid >> 6;
  const int quad = lane >> 4, l15 = lane & 15;
  const long bm = (long)blockIdx.y * 256, bn = (long)blockIdx.x * 256;
  const int wm = (w >> 2) * 128, wn = (w & 3) * 64;
  const int NT = K >> 6;

  const int u0 = tid, u1 = tid + 512;
  const int ar0 = u0 >> 2, ar1 = u1 >> 2;
  const int aq0 = (u0 & 3) ^ (ar0 & 3), aq1 = (u1 & 3) ^ (ar1 & 3);
  const u16* gA0 = A + (bm + ar0) * (long)K + aq0 * 8;
  const u16* gA1 = A + (bm + ar1) * (long)K + aq1 * 8;
  const u16* gB0 = Bw + (bn + ar0) * (long)K + aq0 * 8;
  const u16* gB1 = Bw + (bn + ar1) * (long)K + aq1 * 8;

  const int qx = (quad ^ (l15 & 3)) * 8;
  const int roA = (wm + l15) * 32 + qx;
  const int roB = (wn + l15) * 32 + qx;

  f4_t acc[8][4];
#pragma unroll
  for (int i = 0; i < 8; i++)
#pragma unroll
    for (int j = 0; j < 4; j++) acc[i][j] = (f4_t){0.f, 0.f, 0.f, 0.f};

#define STG_A(buf, s, tt)                                   \
  {                                                         \
    long ko = ((long)(tt) << 6) + ((s) << 5);               \
    gload16(gA0 + ko, &L[buf][0][s][u0 * 8]);               \
    gload16(gA1 + ko, &L[buf][0][s][u1 * 8]);               \
  }
#define STG_B(buf, s, tt)                                   \
  {                                                         \
    long ko = ((long)(tt) << 6) + ((s) << 5);               \
    gload16(gB0 + ko, &L[buf][1][s][u0 * 8]);               \
    gload16(gB1 + ko, &L[buf][1][s][u1 * 8]);               \
  }
#define LDA4(P, o)                                          \
  _Pragma("unroll") for (int i = 0; i < 4; i++)             \
      aF[i] = *(const bf8_t*)((P) + roA + ((o) + i) * 512);
#define LDB4(P)                                             \
  _Pragma("unroll") for (int j = 0; j < 4; j++)             \
      bF[j] = *(const bf8_t*)((P) + roB + j * 512);
#define MFMA_BLK(base)                                      \
  __builtin_amdgcn_s_setprio(1);                            \
  _Pragma("unroll") for (int i = 0; i < 4; i++)             \
      _Pragma("unroll") for (int j = 0; j < 4; j++)         \
          acc[(base) + i][j] = MFMA16(aF[i], bF[j], acc[(base) + i][j]); \
  __builtin_amdgcn_s_setprio(0);
#define SBAR __builtin_amdgcn_s_barrier()

  STG_A(0, 0, 0); STG_B(0, 0, 0);
  STG_A(0, 1, 0); STG_B(0, 1, 0);
  if (NT > 1) { STG_A(1, 0, 1); STG_B(1, 0, 1); }
  asm volatile("s_waitcnt vmcnt(8)" ::: "memory");
  SBAR;

  bf8_t aF[4], bF[4];
  for (int t = 0; t < NT; ++t) {
    const int buf = t & 1;
    const u16* A0 = &L[buf][0][0][0];
    const u16* B0 = &L[buf][1][0][0];
    const u16* A1 = &L[buf][0][1][0];
    const u16* B1 = &L[buf][1][1][0];
    // ---- phase 1 ----
    LDA4(A0, 0);
    LDB4(B0);
    if (t + 1 < NT) STG_A(buf ^ 1, 1, t + 1);
    SBAR;
    asm volatile("s_waitcnt lgkmcnt(0)" ::: "memory");
    MFMA_BLK(0);
    SBAR;
    // ---- phase 2 ----
    LDA4(A0, 4);
    if (t + 1 < NT) STG_B(buf ^ 1, 1, t + 1);
    SBAR;
    asm volatile("s_waitcnt lgkmcnt(0)" ::: "memory");
    MFMA_BLK(4);
    if (t == NT - 1) asm volatile("s_waitcnt vmcnt(0)" ::: "memory");
    else asm volatile("s_waitcnt vmcnt(8)" ::: "memory");
    SBAR;
    // ---- phase 3 ----
    LDA4(A1, 0);
    LDB4(B1);
    if (t + 2 < NT) STG_A(buf, 0, t + 2);
    SBAR;
    asm volatile("s_waitcnt lgkmcnt(0)" ::: "memory");
    MFMA_BLK(0);
    SBAR;
    // ---- phase 4 ----
    LDA4(A1, 4);
    if (t + 2 < NT) STG_B(buf, 0, t + 2);
    SBAR;
    asm volatile("s_waitcnt lgkmcnt(0)" ::: "memory");
    MFMA_BLK(4);
    if (t == NT - 2) asm volatile("s_waitcnt vmcnt(4)" ::: "memory");
    else if (t < NT - 2) asm volatile("s_waitcnt vmcnt(8)" ::: "memory");
    SBAR;
  }

#pragma unroll
  for (int i = 0; i < 8; i++) {
#pragma unroll
    for (int rg = 0; rg < 4; rg++) {
      long mm = bm + wm + i * 16 + quad * 4 + rg;
      long crow = (mm < rsp) ? (mm + r0off) : (mm + r1off);
#pragma unroll
      for (int j = 0; j < 4; j++) {
        long n = bn + wn + j * 16 + l15;
        float x = acc[i][j][rg];
        if (MODE == 0) ((float*)Cv)[crow * (long)N + n] = x;
        else ((u16*)Cv)[crow * (long)N + n] = f2bf(x);
      }
    }
  }
#undef STG_A
#undef STG_B
#undef LDA4
#undef LDB4
#undef MFMA_BLK
#undef SBAR
}

// ---------------- post-GEMM elementwise (fused logits + v_first lerp) ----------------
__global__ __launch_bounds__(256) void post1_kernel(
    const float* __restrict__ F1, const float* __restrict__ F0F4, float* __restrict__ W,
    const float* __restrict__ F2, const u16* __restrict__ VL,
    const float* __restrict__ vfirst,
    u16* __restrict__ KM, u16* __restrict__ KK, u16* __restrict__ BB, u16* __restrict__ VB,
    const float* __restrict__ k_k, const float* __restrict__ k_a,
    const float* __restrict__ wb, const float* __restrict__ ab, int t0, int Tc) {
  const int lane = threadIdx.x & 63;
  const long th = (((long)blockIdx.x * 256) + threadIdx.x) >> 6;
  const int hcol = (int)(th & 31) * 64 + lane;
  const long idx = th * 64 + lane;
  const long r = th >> 5;
  float kraw = F1[idx];
  float kk0 = kraw * k_k[hcol];
  float ss = kk0 * kk0;
#pragma unroll
  for (int m = 32; m; m >>= 1) ss += __shfl_xor(ss, m, 64);
  float kkn = kk0 / fmaxf(sqrtf(ss), 1e-12f);
  float wlog = F0F4[r * 4096 + hcol];
  float alog = F0F4[r * 4096 + 2048 + hcol];
  float av = sigf(alog + ab[hcol]);
  float w = -0.6065306597126334f * sigf(wlog + wb[hcol]);
  W[idx] = w;
  KM[idx] = f2bf(kraw * (1.f + (av - 1.f) * k_a[hcol]));
  KK[idx] = f2bf(kkn);
  BB[idx] = f2bf(kkn * av);
  float vraw = F2[idx];
  float sg = bf2f(VL[idx]);
  long vfi = ((r / Tc) * 4096 + t0 + (r % Tc)) * 2048 + hcol;
  VB[idx] = f2bf(vraw + (vfirst[vfi] - vraw) * sg);
}

// ================= chunked RWKV7 scan (L=16) =================
constexpr int ST64 = 72;   // u16 stride for [16][64]
constexpr int ST32 = 40;   // u16 stride for [.][32]
constexpr int STX = 132;   // fp32 stride for X [16][128]

__global__ __launch_bounds__(64) void phaseA_kernel(
    const float* __restrict__ wS, const u16* __restrict__ kmS, const u16* __restrict__ kkS,
    const u16* __restrict__ bbS, const u16* __restrict__ vbS, const u16* __restrict__ rbS,
    float* __restrict__ POWb, u16* __restrict__ PAb, float* __restrict__ Zb,
    u16* __restrict__ GTb, float* __restrict__ CLb, int Tc, int sp0) {
  __shared__ u16 lXa[16 * ST64], lXr[16 * ST64], lYa[16 * ST64], lYb[16 * ST64];
  __shared__ u16 lYaT[64 * ST32], lYbT[64 * ST32], lVmT[64 * ST32];
  __shared__ u16 lTWt[64 * ST32], lTAt[64 * ST32];
  __shared__ u16 lP[16 * ST32], lQ[16 * ST32], lBm[16 * ST32];
  __shared__ float lA[16 * 16];
  __shared__ float lX[16 * STX];
  __shared__ float lcl[64];
  const int lane = threadIdx.x;
  const int quad = lane >> 4, l15 = lane & 15;
  const long tile = blockIdx.x;
  const int bh = (int)(tile & 63);
  const int col = (int)(tile >> 6);
  const int b = bh >> 5, h = bh & 31;
  const long s = tile;
  const f4_t z4 = {0.f, 0.f, 0.f, 0.f};

  {
    u32* p0 = (u32*)&lYaT[lane * ST32 + 16];
    u32* p1 = (u32*)&lYbT[lane * ST32 + 16];
    u32* p2 = (u32*)&lVmT[lane * ST32 + 16];
    u32* p3 = (u32*)&lTWt[lane * ST32 + 16];
    u32* p4 = (u32*)&lTAt[lane * ST32 + 16];
#pragma unroll
    for (int q = 0; q < 8; q++) { p0[q] = 0; p1[q] = 0; p2[q] = 0; p3[q] = 0; p4[q] = 0; }
    if (lane < 16) {
      u32* q0 = (u32*)&lP[lane * ST32 + 16];
      u32* q1 = (u32*)&lQ[lane * ST32 + 16];
      u32* q2 = (u32*)&lBm[lane * ST32 + 16];
#pragma unroll
      for (int q = 0; q < 8; q++) { q0[q] = 0; q1[q] = 0; q2[q] = 0; }
    }
  }

  const long rowbase = (long)b * Tc + (long)(sp0 + col) * 16;
  const long gbase = rowbase * 2048 + (long)h * 64 + lane;
  float cw = 0.f;
#pragma unroll
  for (int i = 0; i < 16; i++) {
    long g = gbase + (long)i * 2048;
    float w = wS[g];
    float km = bf2f(kmS[g]), kk = bf2f(kkS[g]), bb = bf2f(bbS[g]);
    float vv = bf2f(vbS[g]), rr2 = bf2f(rbS[g]);
    float cwm = cw;
    cw += w;
    float E1 = __expf(cwm), E2 = __expf(-cw), E3 = __expf(cw);
    float xa = -kk * E1;
    lXa[i * ST64 + lane] = f2bf(xa);
    lX[i * STX + 64 + lane] = xa;
    lXr[i * ST64 + lane] = f2bf(rr2 * E3);
    float ya = bb * E2, yb = km * E2;
    lYa[i * ST64 + lane] = f2bf(ya);
    lYb[i * ST64 + lane] = f2bf(yb);
    lYaT[lane * ST32 + i] = f2bf(ya);
    lYbT[lane * ST32 + i] = f2bf(yb);
    lVmT[lane * ST32 + i] = f2bf(vv);
    if (i == 15) { lcl[lane] = E3; CLb[s * 64 + lane] = E3; }
  }
  __syncthreads();

  {
    f4_t aA = z4, aB = z4, aP = z4, aQ = z4;
#pragma unroll
    for (int kc = 0; kc < 2; kc++) {
      bf8_t xa = *(const bf8_t*)&lXa[l15 * ST64 + quad * 8 + 32 * kc];
      bf8_t xr = *(const bf8_t*)&lXr[l15 * ST64 + quad * 8 + 32 * kc];
      bf8_t ya = *(const bf8_t*)&lYa[l15 * ST64 + quad * 8 + 32 * kc];
      bf8_t yb = *(const bf8_t*)&lYb[l15 * ST64 + quad * 8 + 32 * kc];
      aA = MFMA16(xa, ya, aA);
      aB = MFMA16(xa, yb, aB);
      aP = MFMA16(xr, ya, aP);
      aQ = MFMA16(xr, yb, aQ);
    }
#pragma unroll
    for (int rg = 0; rg < 4; rg++) {
      int m = quad * 4 + rg;
      lA[m * 16 + l15] = (l15 < m) ? aA[rg] : 0.f;
      lBm[m * ST32 + l15] = (l15 < m) ? f2bf(aB[rg]) : (u16)0;
      lP[m * ST32 + l15] = (l15 <= m) ? f2bf(aP[rg]) : (u16)0;
      lQ[m * ST32 + l15] = (l15 <= m) ? f2bf(aQ[rg]) : (u16)0;
    }
  }
  __syncthreads();

#pragma unroll
  for (int nt = 0; nt < 4; nt++) {
    f4_t acc = z4;
    bf8_t a = *(const bf8_t*)&lBm[l15 * ST32 + quad * 8];
    bf8_t bb2 = *(const bf8_t*)&lVmT[(nt * 16 + l15) * ST32 + quad * 8];
    acc = MFMA16(a, bb2, acc);
#pragma unroll
    for (int rg = 0; rg < 4; rg++) lX[(quad * 4 + rg) * STX + nt * 16 + l15] = acc[rg];
  }
  __syncthreads();

  for (int i = 1; i < 16; i++) {
    float x0 = lX[i * STX + lane], x1 = lX[i * STX + 64 + lane];
    for (int j = 0; j < i; j++) {
      float aij = lA[i * 16 + j];
      x0 += aij * lX[j * STX + lane];
      x1 += aij * lX[j * STX + 64 + lane];
    }
    lX[i * STX + lane] = x0;
    lX[i * STX + 64 + lane] = x1;
  }
#pragma unroll
  for (int i = 0; i < 16; i++) {
    lTWt[lane * ST32 + i] = f2bf(lX[i * STX + lane]);
    lTAt[lane * ST32 + i] = f2bf(lX[i * STX + 64 + lane]);
  }
  __syncthreads();

#pragma unroll
  for (int nt = 0; nt < 4; nt++) {
    f4_t acc = z4;
    bf8_t p = *(const bf8_t*)&lP[l15 * ST32 + quad * 8];
    bf8_t q = *(const bf8_t*)&lQ[l15 * ST32 + quad * 8];
    bf8_t tw = *(const bf8_t*)&lTWt[(nt * 16 + l15) * ST32 + quad * 8];
    bf8_t vm = *(const bf8_t*)&lVmT[(nt * 16 + l15) * ST32 + quad * 8];
    acc = MFMA16(p, tw, acc);
    acc = MFMA16(q, vm, acc);
#pragma unroll
    for (int rg = 0; rg < 4; rg++)
      POWb[s * 1024 + (quad * 4 + rg) * 64 + nt * 16 + l15] = acc[rg];
  }
#pragma unroll
  for (int nt = 0; nt < 4; nt++) {
    f4_t acc = z4;
    bf8_t p = *(const bf8_t*)&lP[l15 * ST32 + quad * 8];
    bf8_t ta = *(const bf8_t*)&lTAt[(nt * 16 + l15) * ST32 + quad * 8];
    acc = MFMA16(p, ta, acc);
#pragma unroll
    for (int rg = 0; rg < 4; rg++) {
      float xr = bf2f(lXr[(quad * 4 + rg) * ST64 + nt * 16 + l15]);
      PAb[s * 1024 + (quad * 4 + rg) * 64 + nt * 16 + l15] = f2bf(acc[rg] + xr);
    }
  }

#pragma unroll
  for (int mt = 0; mt < 4; mt++)
#pragma unroll
    for (int nt = 0; nt < 4; nt++) {
      f4_t acc = z4;
      bf8_t tw = *(const bf8_t*)&lTWt[(mt * 16 + l15) * ST32 + quad * 8];
      bf8_t vm = *(const bf8_t*)&lVmT[(mt * 16 + l15) * ST32 + quad * 8];
      bf8_t yat = *(const bf8_t*)&lYaT[(nt * 16 + l15) * ST32 + quad * 8];
      bf8_t ybt = *(const bf8_t*)&lYbT[(nt * 16 + l15) * ST32 + quad * 8];
      acc = MFMA16(tw, yat, acc);
      acc = MFMA16(vm, ybt, acc);
      float cl = lcl[nt * 16 + l15];
#pragma unroll
      for (int rg = 0; rg < 4; rg++)
        Zb[s * 4096 + (mt * 16 + quad * 4 + rg) * 64 + nt * 16 + l15] = acc[rg] * cl;
    }
#pragma unroll
  for (int mt = 0; mt < 4; mt++)
#pragma unroll
    for (int nt = 0; nt < 4; nt++) {
      f4_t acc = z4;
      bf8_t yat = *(const bf8_t*)&lYaT[(mt * 16 + l15) * ST32 + quad * 8];
      bf8_t ta = *(const bf8_t*)&lTAt[(nt * 16 + l15) * ST32 + quad * 8];
      acc = MFMA16(yat, ta, acc);
#pragma unroll
      for (int rg = 0; rg < 4; rg++) {
        float cl = lcl[mt * 16 + quad * 4 + rg];
        GTb[s * 4096 + (mt * 16 + quad * 4 + rg) * 64 + nt * 16 + l15] = f2bf(acc[rg] * cl);
      }
    }
}

// phase B: sequential state propagation per (b,h) with 2-step register prefetch.
// S_new = S*cl + S@G + Z. CT is always even (8/16/32/64).
__global__ __launch_bounds__(256) void phaseB_kernel(
    const float* __restrict__ Zb, const u16* __restrict__ GTb, const float* __restrict__ CLb,
    u16* __restrict__ S0b, float* __restrict__ state, int CT, int init) {
  __shared__ u16 Sb[64 * ST64];
  const int bh = blockIdx.x;
  const int tid = threadIdx.x, wv = tid >> 6, lane = tid & 63;
  const int quad = lane >> 4, l15 = lane & 15;
  float S[4][4];
  if (init) {
#pragma unroll
    for (int nt = 0; nt < 4; nt++)
#pragma unroll
      for (int rg = 0; rg < 4; rg++) S[nt][rg] = 0.f;
  } else {
#pragma unroll
    for (int nt = 0; nt < 4; nt++)
#pragma unroll
      for (int rg = 0; rg < 4; rg++)
        S[nt][rg] = state[(long)bh * 4096 + (16 * wv + quad * 4 + rg) * 64 + nt * 16 + l15];
  }
  const f4_t z4 = {0.f, 0.f, 0.f, 0.f};

  uint4 gtA[2][4], gtB[2][4];
  float zA[4][4], zB[4][4], clA[4], clB[4];

#define LOADSET(cc, gt, z, cl)                                                      \
  {                                                                                 \
    long s2 = (long)(cc) * 64 + bh;                                                 \
    _Pragma("unroll") for (int kc = 0; kc < 2; kc++)                                \
        _Pragma("unroll") for (int nt = 0; nt < 4; nt++)                            \
            gt[kc][nt] = *(const uint4*)(GTb + s2 * 4096 + (nt * 16 + l15) * 64 + quad * 8 + 32 * kc); \
    _Pragma("unroll") for (int nt = 0; nt < 4; nt++) {                              \
      cl[nt] = CLb[s2 * 64 + nt * 16 + l15];                                        \
      _Pragma("unroll") for (int rg = 0; rg < 4; rg++)                              \
          z[nt][rg] = Zb[s2 * 4096 + (16 * wv + quad * 4 + rg) * 64 + nt * 16 + l15]; \
    }                                                                               \
  }
#define BSTEP(cc, gt, z, cl, gtN, zN, clN, pf)                                      \
  {                                                                                 \
    long s1 = (long)(cc) * 64 + bh;                                                 \
    _Pragma("unroll") for (int nt = 0; nt < 4; nt++)                                \
        _Pragma("unroll") for (int rg = 0; rg < 4; rg++)                            \
            Sb[(16 * wv + quad * 4 + rg) * ST64 + nt * 16 + l15] = f2bf(S[nt][rg]); \
    __syncthreads();                                                                \
    if (pf) LOADSET((cc) + 1, gtN, zN, clN);                                        \
    f4_t acc[4] = {z4, z4, z4, z4};                                                 \
    _Pragma("unroll") for (int kc = 0; kc < 2; kc++) {                              \
      bf8_t a = *(const bf8_t*)&Sb[(16 * wv + l15) * ST64 + quad * 8 + 32 * kc];    \
      *(uint4*)(S0b + s1 * 4096 + (16 * wv + l15) * 64 + quad * 8 + 32 * kc) = *(uint4*)&a; \
      _Pragma("unroll") for (int nt = 0; nt < 4; nt++) {                            \
        bf8_t g = *(const bf8_t*)&gt[kc][nt];                                       \
        acc[nt] = MFMA16(a, g, acc[nt]);                                            \
      }                                                                             \
    }                                                                               \
    _Pragma("unroll") for (int nt = 0; nt < 4; nt++)                                \
        _Pragma("unroll") for (int rg = 0; rg < 4; rg++)                            \
            S[nt][rg] = S[nt][rg] * cl[nt] + acc[nt][rg] + z[nt][rg];               \
    __syncthreads();                                                                \
  }

  LOADSET(0, gtA, zA, clA);
  for (int c = 0; c < CT; c += 2) {
    BSTEP(c, gtA, zA, clA, gtB, zB, clB, (c + 1 < CT));
    BSTEP(c + 1, gtB, zB, clB, gtA, zA, clA, (c + 2 < CT));
  }
#undef LOADSET
#undef BSTEP
#pragma unroll
  for (int nt = 0; nt < 4; nt++)
#pragma unroll
    for (int rg = 0; rg < 4; rg++)
      state[(long)bh * 4096 + (16 * wv + quad * 4 + rg) * 64 + nt * 16 + l15] = S[nt][rg];
}

// phase C: O = POW + PA * S0^T
__global__ __launch_bounds__(64) void phaseC_kernel(
    const float* __restrict__ POWb, const u16* __restrict__ PAb, const u16* __restrict__ S0b,
    float* __restrict__ O, int Tc, int sp0) {
  const int lane = threadIdx.x, quad = lane >> 4, l15 = lane & 15;
  const long tile = blockIdx.x;
  const int bh = (int)(tile & 63), col = (int)(tile >> 6);
  const int b = bh >> 5, h = bh & 31;
  const long s = tile;
  const f4_t z4 = {0.f, 0.f, 0.f, 0.f};
  f4_t acc[4] = {z4, z4, z4, z4};
#pragma unroll
  for (int kc = 0; kc < 2; kc++) {
    bf8_t a = *(const bf8_t*)(PAb + s * 1024 + l15 * 64 + quad * 8 + 32 * kc);
#pragma unroll
    for (int nt = 0; nt < 4; nt++) {
      bf8_t bo = *(const bf8_t*)(S0b + s * 4096 + (nt * 16 + l15) * 64 + quad * 8 + 32 * kc);
      acc[nt] = MFMA16(a, bo, acc[nt]);
    }
  }
  const long rowbase = (long)b * Tc + (long)(sp0 + col) * 16;
#pragma unroll
  for (int nt = 0; nt < 4; nt++)
#pragma unroll
    for (int rg = 0; rg < 4; rg++) {
      int i = quad * 4 + rg, v = nt * 16 + l15;
      float p = POWb[s * 1024 + i * 64 + v];
      O[(rowbase + i) * 2048 + (long)h * 64 + v] = p + acc[nt][rg];
    }
}

// ---------------- group-norm + residual + gate ----------------
__global__ __launch_bounds__(256) void epi_kernel(
    const float* __restrict__ o, const u16* __restrict__ r, const u16* __restrict__ k,
    const u16* __restrict__ v, const u16* __restrict__ g,
    const float* __restrict__ r_k, const float* __restrict__ gn_w, const float* __restrict__ gn_b,
    u16* __restrict__ y) {
  const int lane = threadIdx.x & 63;
  const long th = (((long)blockIdx.x * 256) + threadIdx.x) >> 6;
  const int hcol = (int)(th & 31) * 64 + lane;
  const long idx = th * 64 + lane;
  float ov = o[idx];
  float s = ov;
#pragma unroll
  for (int m = 32; m; m >>= 1) s += __shfl_xor(s, m, 64);
  float mu = s * (1.f / 64.f);
  float d = ov - mu;
  float vs = d * d;
#pragma unroll
  for (int m = 32; m; m >>= 1) vs += __shfl_xor(vs, m, 64);
  float on = d * rsqrtf(vs * (1.f / 64.f) + 6.4e-4f);
  on = on * gn_w[hcol] + gn_b[hcol];
  float rk = bf2f(r[idx]) * bf2f(k[idx]) * r_k[hcol];
#pragma unroll
  for (int m = 32; m; m >>= 1) rk += __shfl_xor(rk, m, 64);
  on += rk * bf2f(v[idx]);
  y[idx] = f2bf(on * bf2f(g[idx]));
}

// =============================== host ===============================
extern "C" void kernel_launch(void* const* d_in, const int* in_sizes, int n_in,
                              void* d_out, int out_size, void* d_ws, size_t ws_size,
                              hipStream_t stream) {
  constexpr int B = 2, T = 4096, H = 2048;
  const float* hst    = (const float*)d_in[0];
  const float* vfirst = (const float*)d_in[1];
  const float* x_r = (const float*)d_in[2];
  const float* x_w = (const float*)d_in[3];
  const float* x_k = (const float*)d_in[4];
  const float* x_v = (const float*)d_in[5];
  const float* x_a = (const float*)d_in[6];
  const float* x_g = (const float*)d_in[7];
  const float* k_k = (const float*)d_in[8];
  const float* k_a = (const float*)d_in[9];
  const float* r_k = (const float*)d_in[10];
  const float* w_r = (const float*)d_in[11];
  const float* w_k = (const float*)d_in[12];
  const float* w_v = (const float*)d_in[13];
  const float* w_o = (const float*)d_in[14];
  const float* wA  = (const float*)d_in[15];
  const float* wB  = (const float*)d_in[16];
  const float* wb  = (const float*)d_in[17];
  const float* aA  = (const float*)d_in[18];
  const float* aB  = (const float*)d_in[19];
  const float* ab  = (const float*)d_in[20];
  const float* vA  = (const float*)d_in[21];
  const float* vB  = (const float*)d_in[22];
  const float* vb  = (const float*)d_in[23];
  const float* gA  = (const float*)d_in[24];
  const float* gB  = (const float*)d_in[25];
  const float* gn_w= (const float*)d_in[26];
  const float* gn_b= (const float*)d_in[27];

  const size_t WEIGHT_BYTES = 4 * (size_t)H * H * 2 + (size_t)H * 128 * 2
                            + (size_t)H * 256 * 2 + (size_t)768 * 4096 * 2
                            + (size_t)4096 * 256 * 2;
  const size_t STATE_BYTES = (size_t)64 * 4096 * 4;
  const size_t TILE_BYTES = 4096 + 2048 + 16384 + 8192 + 256 + 8192;  // POW PA Z GT CL S0

  int NC = -1, CT = 0;
  for (int pass = 0; pass < 2 && NC < 0; pass++) {
    for (int nc : {1, 2, 4, 8, 16}) {
      long Tc_ = T / nc;
      long R_ = (long)B * Tc_;
      long RH_ = R_ * H;
      // fp32: F0F4(8)+F1(4)+F2(4)+W(4) = RH*20 ; bf16 bufs RH*16 ; HD RH*4 ; s1all
      size_t base = (size_t)RH_ * 40 + (size_t)R_ * 1536
                  + WEIGHT_BYTES + STATE_BYTES + (4 << 20);
      int cols = (int)(Tc_ / 16);
      int found = 0;
      for (int ct : {64, 32, 16, 8}) {
        if (ct > cols) continue;
        if (pass == 0 && ct < 16) continue;
        size_t need = base + (size_t)64 * ct * TILE_BYTES;
        if (need <= ws_size) { NC = nc; CT = ct; found = 1; break; }
      }
      if (found) break;
    }
  }
  const int BS = 256;
  auto cdiv = [](long a, long b) { return (int)((a + b - 1) / b); };
  if (NC < 0) {
    fill_kernel<<<cdiv(out_size, BS), BS, 0, stream>>>(
        (float*)d_out, 200000.f + (float)(ws_size >> 20), out_size);
    return;
  }
  const int Tc = T / NC;
  const long R = (long)B * Tc;
  const long RH = R * H;
  const int cols = Tc / 16;
  const int NTILE = 64 * CT;

  char* ws = (char*)d_ws;
  size_t off = 0;
  auto alloc = [&](size_t bytes) -> void* {
    void* p = ws + off;
    off += (bytes + 255) & ~(size_t)255;
    return p;
  };
  float* F0F4 = (float*)alloc(RH * 8);      // fused [w-logit | a-logit], R x 4096
  float* F1 = (float*)alloc(RH * 4);
  float* F2 = (float*)alloc(RH * 4);
  float* W  = (float*)alloc(RH * 4);        // decoded log-decay, R x 2048
  u16* KM  = (u16*)alloc(RH * 2);
  u16* KK  = (u16*)alloc(RH * 2);
  u16* BBs = (u16*)alloc(RH * 2);
  u16* VBs = (u16*)alloc(RH * 2);
  u16* RBs = (u16*)alloc(RH * 2);
  u16* MIXB = (u16*)alloc(RH * 2);
  u16* G    = (u16*)alloc(RH * 2);
  u16* VL   = (u16*)alloc(RH * 2);
  u16* HD   = (u16*)alloc(RH * 4);
  u16* s1all = (u16*)alloc(R * 1536);
  u16* wrb = (u16*)alloc((size_t)H * H * 2);
  u16* wkb = (u16*)alloc((size_t)H * H * 2);
  u16* wvb = (u16*)alloc((size_t)H * H * 2);
  u16* wob = (u16*)alloc((size_t)H * H * 2);
  u16* vBb = (u16*)alloc((size_t)H * 128 * 2);
  u16* gBb = (u16*)alloc((size_t)H * 256 * 2);
  u16* Wf  = (u16*)alloc((size_t)768 * 4096 * 2);
  u16* Wab = (u16*)alloc((size_t)4096 * 256 * 2);
  float* state = (float*)alloc(STATE_BYTES);
  float* POWb = (float*)alloc((size_t)NTILE * 4096);
  u16*   PAb  = (u16*)alloc((size_t)NTILE * 2048);
  float* Zb   = (float*)alloc((size_t)NTILE * 16384);
  u16*   GTb  = (u16*)alloc((size_t)NTILE * 8192);
  float* CLb  = (float*)alloc((size_t)NTILE * 256);
  u16*   S0b  = (u16*)alloc((size_t)NTILE * 8192);
  float* Ob = F1;

  // big weights -> bf16 (once)
  padcvt_kernel<<<cdiv((long)H * H, BS), BS, 0, stream>>>(w_r, wrb, H, H, H, (long)H * H);
  padcvt_kernel<<<cdiv((long)H * H, BS), BS, 0, stream>>>(w_k, wkb, H, H, H, (long)H * H);
  padcvt_kernel<<<cdiv((long)H * H, BS), BS, 0, stream>>>(w_v, wvb, H, H, H, (long)H * H);
  padcvt_kernel<<<cdiv((long)H * H, BS), BS, 0, stream>>>(w_o, wob, H, H, H, (long)H * H);
  padcvt_kernel<<<cdiv((long)H * 128, BS), BS, 0, stream>>>(vB, vBb, H, 64, 128, (long)H * 128);
  padcvt_kernel<<<cdiv((long)H * 256, BS), BS, 0, stream>>>(gB, gBb, H, 256, 256, (long)H * 256);
  // fused stage1 weight stack
  wf_kernel<<<cdiv((long)128 * 4096, BS), BS, 0, stream>>>(wA, x_w, Wf, 96, 0, (long)128 * 4096);
  wf_kernel<<<cdiv((long)128 * 4096, BS), BS, 0, stream>>>(aA, x_a, Wf, 96, 128, (long)128 * 4096);
  wf_kernel<<<cdiv((long)128 * 4096, BS), BS, 0, stream>>>(vA, x_v, Wf, 64, 256, (long)128 * 4096);
  wf_kernel<<<cdiv((long)384 * 4096, BS), BS, 0, stream>>>(gA, x_g, Wf, 256, 384, (long)384 * 4096);
  // block-diag stacked stage2 weight [wB ; aB]
  wab_kernel<<<cdiv((long)4096 * 256, BS), BS, 0, stream>>>(wB, aB, Wab, (long)4096 * 256);

  const long mixTot = (long)Tc * H / 4;
  const int mixG = cdiv(mixTot, BS);
  const int ehG = (int)(R * 32 / 4);

  for (int c = 0; c < NC; c++) {
    const int t0 = c * Tc;
    auto MIX = [&](const float* coef) {
      for (int b = 0; b < B; b++)
        mix1_kernel<<<mixG, BS, 0, stream>>>(hst + (long)b * T * H, coef,
                                             MIXB + (long)b * Tc * H, t0, Tc, mixTot);
    };
    dim3 gBig(16, (unsigned)(R / 128)), gF(6, (unsigned)(R / 128)), gWA(32, (unsigned)(R / 128));
    dim3 g256((unsigned)(H / 256), (unsigned)(R / 256));

    // HD = [h | delta]
    for (int b = 0; b < B; b++)
      hd_kernel<<<mixG, BS, 0, stream>>>(hst + (long)b * T * H,
                                         HD + (long)b * Tc * 4096, t0, Tc, mixTot);
    // fused stage1
    gemm_bt<5><<<gF, 256, 0, stream>>>(HD, Wf, s1all, (int)R, 768, 4096, 4096, nullptr);
    // merged stage2 (w | a) -> F0F4
    gemm_bt<0><<<gWA, 256, 0, stream>>>(s1all, Wab, F0F4, (int)R, 4096, 256, 768, nullptr);
    // v: raw proj + gate (lerp folded into post1)
    MIX(x_v);
    gemm256_bt<0><<<g256, 512, 0, stream>>>(MIXB, wvb, F2, (int)R, H, H, (int)R, 0, 0);
    gemm_bt<6><<<gBig, 256, 0, stream>>>(s1all + 256, vBb, VL, (int)R, H, 128, 768, vb);
    // g stage2 -> G
    gemm_bt<1><<<gBig, 256, 0, stream>>>(s1all + 384, gBb, G, (int)R, H, 256, 768, nullptr);
    // r -> RBs, k -> F1
    MIX(x_r);
    gemm256_bt<1><<<g256, 512, 0, stream>>>(MIXB, wrb, RBs, (int)R, H, H, (int)R, 0, 0);
    MIX(x_k);
    gemm256_bt<0><<<g256, 512, 0, stream>>>(MIXB, wkb, F1, (int)R, H, H, (int)R, 0, 0);
    // elementwise (logit decode + v_first lerp)
    post1_kernel<<<ehG, 256, 0, stream>>>(F1, F0F4, W, F2, VL, vfirst,
                                          KM, KK, BBs, VBs, k_k, k_a, wb, ab, t0, Tc);
    // chunked scan
    for (int sp = 0; sp < cols; sp += CT) {
      phaseA_kernel<<<NTILE, 64, 0, stream>>>(W, KM, KK, BBs, VBs, RBs,
                                              POWb, PAb, Zb, GTb, CLb, Tc, sp);
      phaseB_kernel<<<64, 256, 0, stream>>>(Zb, GTb, CLb, S0b, state, CT,
                                            (c == 0 && sp == 0) ? 1 : 0);
      phaseC_kernel<<<NTILE, 64, 0, stream>>>(POWb, PAb, S0b, Ob, Tc, sp);
    }
    // groupnorm + residual + gate -> MIXB
    epi_kernel<<<ehG, 256, 0, stream>>>(Ob, RBs, KM, VBs, G, r_k, gn_w, gn_b, MIXB);
    // output projection
    gemm256_bt<0><<<g256, 512, 0, stream>>>(MIXB, wob, (float*)d_out, (int)R, H, H,
                                            Tc, (long)t0, (long)T - Tc + t0);
  }
}